// Round 4
// baseline (759.730 us; speedup 1.0000x reference)
//
#include <hip/hip_runtime.h>
#include <stdint.h>

// Problem constants
#define NB   256     // batch
#define NT   192     // frames
#define NH   64      // hidden
#define NC   256     // conv channels / scan steps
#define NOUT 28
#define K2   1536    // conv2 reduction = 256ci * 6y (re-keyed as y*256+ci)

typedef __attribute__((ext_vector_type(8))) short short8v;  // 8 bf16 (4 VGPR)
typedef __attribute__((ext_vector_type(4))) float f32x4;    // MFMA acc

// ---------- helpers ----------
__device__ __forceinline__ float lane_bcast(float v, int m) {
    return __int_as_float(__builtin_amdgcn_readlane(__float_as_int(v), m));
}
__device__ __forceinline__ uint16_t f2bf(float f) {          // RNE f32->bf16
    uint32_t u = __float_as_uint(f);
    return (uint16_t)((u + 0x7fffu + ((u >> 16) & 1u)) >> 16);
}
__device__ __forceinline__ uint32_t pk2(float a, float b) {
    return (uint32_t)f2bf(a) | ((uint32_t)f2bf(b) << 16);
}
__device__ __forceinline__ float bf2f(uint16_t u) {
    return __uint_as_float((uint32_t)u << 16);
}
__device__ __forceinline__ float sigmoidf_(float x) { return 1.f / (1.f + __expf(-x)); }
__device__ __forceinline__ float tanhf_(float x) {
    float a = fabsf(x);
    float e = __expf(2.f * a);          // inf for large a is fine: 2/(inf+1)=0
    float r = 1.f - 2.f / (e + 1.f);
    return (x < 0.f) ? -r : r;
}
// raw barrier: LDS-ordering only, does NOT drain vmcnt (keeps global prefetch alive)
__device__ __forceinline__ void wg_barrier() {
    asm volatile("s_waitcnt lgkmcnt(0)\n\ts_barrier" ::: "memory");
}
// async global->LDS, 16 B per lane; LDS dest is wave-uniform base + lane*16
__device__ __forceinline__ void gload_lds16(const uint16_t* g, uint16_t* l) {
    __builtin_amdgcn_global_load_lds(
        (const __attribute__((address_space(1))) uint32_t*)(const void*)g,
        (__attribute__((address_space(3))) uint32_t*)(void*)l, 16, 0, 0);
}
// read one MFMA operand fragment from a [rows][64] bf16 LDS tile, XOR-swizzled
__device__ __forceinline__ short8v frag_ld(const uint16_t* tile, int row, int kchunk) {
    const int kc = kchunk ^ (row & 7);
    return *(const short8v*)(tile + row * 64 + kc * 8);
}
// pack 8 consecutive f32 -> short8v (bf16)
__device__ __forceinline__ short8v pack8(const float* p) {
    float4 q0 = *(const float4*)p;
    float4 q1 = *(const float4*)(p + 4);
    union { short8v v; uint32_t u[4]; } r;
    r.u[0] = pk2(q0.x, q0.y); r.u[1] = pk2(q0.z, q0.w);
    r.u[2] = pk2(q1.x, q1.y); r.u[3] = pk2(q1.z, q1.w);
    return r.v;
}

// ---------- K0a: fp32 -> bf16 conversion (n even) ----------
__global__ __launch_bounds__(256) void k_cvt(const float* __restrict__ src,
                                             uint16_t* __restrict__ dst, int n)
{
    int i = blockIdx.x * 256 + threadIdx.x;      // converts 2 elems
    if (2 * i < n) {
        float2 v = *(const float2*)(src + 2 * i);
        ((uint32_t*)dst)[i] = pk2(v.x, v.y);
    }
}

// ---------- K0b: w1 (256,72) fp32 -> w1b_pad (256,104) bf16, k>=72 zero ----------
__global__ __launch_bounds__(256) void k_cvtw1(const float* __restrict__ w1,
                                               uint16_t* __restrict__ dst)
{
    int id = blockIdx.x * 256 + threadIdx.x;     // one u32 pair
    if (id < 256 * 52) {
        int co = id / 52, p = id - co * 52;
        uint32_t v = 0u;
        if (p < 36) {
            float2 q = *(const float2*)(w1 + co * 72 + 2 * p);
            v = pk2(q.x, q.y);
        }
        ((uint32_t*)dst)[id] = v;
    }
}

// ---------- K0c: w2 [co][ci*6+y] fp32 -> w2b [co][y*256+ci] bf16 ----------
__global__ __launch_bounds__(256) void k_cvtw2(const float* __restrict__ w2,
                                               uint16_t* __restrict__ dst)
{
    int id = blockIdx.x * 256 + threadIdx.x;     // one u32 pair
    if (id < 196608) {
        int co  = id / 768;
        int rem = id - co * 768;
        int y   = rem / 128;
        int cp  = rem - y * 128;
        int ci0 = cp * 2;
        float a = w2[(size_t)co * 1536 + ci0 * 6 + y];
        float b = w2[(size_t)co * 1536 + (ci0 + 1) * 6 + y];
        ((uint32_t*)dst)[id] = pk2(a, b);
    }
}

// ---------- K1: conv1 via implicit-GEMM MFMA ----------
// D[co][m=(lt,y)] = sum_{k=(ci,dt,dr,dw)} W[co][k] * P[m][k];  h1 relu'd, k-order y*256+ci
__global__ __launch_bounds__(256) void k_conv1_mfma(const float* __restrict__ x,
                                                    const uint16_t* __restrict__ w1b,
                                                    const float* __restrict__ b1,
                                                    uint16_t* __restrict__ h1)
{
    __shared__ alignas(16) uint16_t Wt[256 * 104];     // 53248 B (DMA, linear)
    __shared__ alignas(16) uint16_t Pt[96 * 100];      // 19200 B (constructed)
    __shared__ alignas(16) float patch[2 * 18 * 64];   //  9216 B [ci][tt][1+f]
    const int tid  = threadIdx.x;
    const int w    = tid >> 6;
    const int lane = tid & 63;
    const int tblk = blockIdx.x;                       // 0..11
    const int b    = blockIdx.y;                       // 0..255
    const int t0   = tblk * 16;

    // 1) issue W DMA: 3328 16B-chunks, 13 per lane
    #pragma unroll
    for (int i = 0; i < 13; i++) {
        const int cbase = i * 256 + w * 64;
        gload_lds16(w1b + (size_t)(cbase + lane) * 8, &Wt[cbase * 8]);
    }

    // 2) stage fp32 patch (frames t0-1 .. t0+16), zero-pad t boundary
    for (int idx = tid; idx < 2 * 18 * 63; idx += 256) {
        int ci  = idx / 1134;
        int rem = idx - ci * 1134;
        int tt  = rem / 63;
        int f   = rem - tt * 63;
        int gf  = t0 - 1 + tt;
        float v = 0.f;
        if (gf >= 0 && gf < NT) v = x[(size_t)b * 24192 + ci * 12096 + gf * 63 + f];
        patch[ci * 1152 + tt * 64 + 1 + f] = v;
    }
    __syncthreads();   // patch ready (also drains W DMA; fine, one-shot kernel)

    // 3) construct P[m][k]: m=lt*6+y, k=cd*12 + (dr*3+dw), cd=(ci,dt); rows stride 100
    for (int l = 0; l < 3; l++) {
        int idx = tid + l * 256;
        if (idx < 576) {
            int m  = idx / 6;
            int cd = idx - m * 6;
            int ci = cd / 3, dt = cd - ci * 3;
            int lt = m / 6,  y  = m - lt * 6;
            const float* pb = &patch[ci * 1152 + (lt + dt) * 64];
            uint2* dst = (uint2*)(Pt + m * 100 + cd * 12);   // 24B, 8B-aligned
            if (y == 0) {   // rows -3..0: dr<3 zero, dr=3 -> pb[1..3]
                dst[0] = (uint2){0u, 0u};
                dst[1] = (uint2){0u, 0u};
                dst[2] = (uint2){(uint32_t)f2bf(pb[1]) << 16, pk2(pb[2], pb[3])};
            } else {
                const float4* q = (const float4*)(pb + 12 * y - 8);
                float4 q0 = q[0], q1 = q[1], q2 = q[2];
                dst[0] = (uint2){pk2(q0.x, q0.y), pk2(q0.z, q0.w)};
                dst[1] = (uint2){pk2(q1.x, q1.y), pk2(q1.z, q1.w)};
                dst[2] = (uint2){pk2(q2.x, q2.y), pk2(q2.z, q2.w)};
            }
        }
    }
    // zero P k-pad 72..95 (both operands' pad zero => safe vs stale LDS)
    {
        int idx = tid;
        if (idx < 192) {
            int m = idx >> 1, half = idx & 1;
            uint2* dst = (uint2*)(Pt + m * 100 + 72 + half * 12);
            dst[0] = (uint2){0u, 0u};
            dst[1] = (uint2){0u, 0u};
            dst[2] = (uint2){0u, 0u};
        }
    }
    wg_barrier();      // P writes visible (W already drained)

    // 4) GEMM: wave w -> co tiles w*4..w*4+3 (64 co) x all 6 m-tiles, 3 K-steps
    f32x4 acc[4][6];
    #pragma unroll
    for (int i = 0; i < 4; i++)
        #pragma unroll
        for (int j = 0; j < 6; j++) acc[i][j] = (f32x4){0.f, 0.f, 0.f, 0.f};

    #pragma unroll
    for (int kstep = 0; kstep < 3; kstep++) {
        const int kch = kstep * 4 + (lane >> 4);       // chunk 0..11
        short8v wf[4], pf[6];
        #pragma unroll
        for (int at = 0; at < 4; at++)
            wf[at] = *(const short8v*)(Wt + ((w * 4 + at) * 16 + (lane & 15)) * 104 + kch * 8);
        #pragma unroll
        for (int mt = 0; mt < 6; mt++)
            pf[mt] = *(const short8v*)(Pt + (mt * 16 + (lane & 15)) * 100 + kch * 8);
        #pragma unroll
        for (int at = 0; at < 4; at++)
            #pragma unroll
            for (int mt = 0; mt < 6; mt++)
                acc[at][mt] = __builtin_amdgcn_mfma_f32_16x16x32_bf16(
                    wf[at], pf[mt], acc[at][mt], 0, 0, 0);
    }

    // 5) epilogue: D layout col(lane&15)=m, row((lane>>4)*4+reg)=co; relu; h1 k=y*256+ci
    #pragma unroll
    for (int mt = 0; mt < 6; mt++) {
        const int m  = mt * 16 + (lane & 15);
        const int lt = m / 6, y = m - lt * 6;
        uint16_t* rowp = h1 + (size_t)(b * NT + t0 + lt) * K2 + y * 256;
        #pragma unroll
        for (int at = 0; at < 4; at++) {
            const int co0 = (w * 4 + at) * 16 + (lane >> 4) * 4;
            float4 b4 = *(const float4*)&b1[co0];
            f32x4 v = acc[at][mt];
            float r0 = fmaxf(v[0] + b4.x, 0.f), r1 = fmaxf(v[1] + b4.y, 0.f);
            float r2 = fmaxf(v[2] + b4.z, 0.f), r3 = fmaxf(v[3] + b4.w, 0.f);
            *(uint2*)(rowp + co0) = (uint2){pk2(r0, r1), pk2(r2, r3)};
        }
    }
}

// ---------- K2: unified bf16 MFMA GEMM ----------
// C[arow][bcol] = sum_k A[arow][k] * B[bcol][k]  (both operands [entity][k] bf16)
// MODE 0 (conv2): A=h1[bt][1536], B=w2b[co][1536]; out=featsb[(b*256+co)][t] bf16 +b2[co]
// MODE 1 (g1pre): A=w_ih1b[g][256], B=featsb[btj][192]; out=g1b[btj][g] bf16 +b_ih1[g]
template<int MODE>
__global__ __launch_bounds__(256) void k_gemm(const uint16_t* __restrict__ A,
                                              const uint16_t* __restrict__ B,
                                              const float* __restrict__ bias,
                                              uint16_t* __restrict__ out,
                                              int kSteps, int lda, int ldb)
{
    __shared__ alignas(16) uint16_t As[2][64 * 64];     // 16 KB
    __shared__ alignas(16) uint16_t Bs[2][256 * 64];    // 64 KB
    const int tid  = threadIdx.x;
    const int w    = tid >> 6;
    const int lane = tid & 63;
    const int a0   = blockIdx.x * 64;
    const int b0   = blockIdx.y * 256;

    f32x4 acc[4][4];
    #pragma unroll
    for (int i = 0; i < 4; i++)
        #pragma unroll
        for (int j = 0; j < 4; j++) acc[i][j] = (f32x4){0.f, 0.f, 0.f, 0.f};

    auto stage = [&](int buf, int k0) {
        #pragma unroll
        for (int i = 0; i < 2; i++) {                    // A: 512 chunks, 2 instr/wave
            int c   = w * 128 + i * 64 + lane;
            int row = c >> 3;
            int kc  = (c & 7) ^ (row & 7);               // inverse swizzle on SOURCE
            gload_lds16(A + (size_t)(a0 + row) * lda + k0 + kc * 8,
                        &As[buf][(w * 128 + i * 64) * 8]);
        }
        #pragma unroll
        for (int i = 0; i < 8; i++) {                    // B: 2048 chunks, 8 instr/wave
            int c   = w * 512 + i * 64 + lane;
            int row = c >> 3;
            int kc  = (c & 7) ^ (row & 7);
            gload_lds16(B + (size_t)(b0 + row) * ldb + k0 + kc * 8,
                        &Bs[buf][(w * 512 + i * 64) * 8]);
        }
    };

    stage(0, 0);
    for (int t = 0; t < kSteps; ++t) {
        const int cur = t & 1;
        if (t + 1 < kSteps) {
            stage(cur ^ 1, (t + 1) * 64);
            asm volatile("s_waitcnt vmcnt(10)" ::: "memory");  // cur's 10 done, next 10 in flight
        } else {
            asm volatile("s_waitcnt vmcnt(0)" ::: "memory");
        }
        __builtin_amdgcn_sched_barrier(0);
        __builtin_amdgcn_s_barrier();
        __builtin_amdgcn_sched_barrier(0);
        #pragma unroll
        for (int ks = 0; ks < 2; ++ks) {
            short8v af[4], bf[4];
            const int kch = ks * 4 + (lane >> 4);
            #pragma unroll
            for (int rt = 0; rt < 4; rt++)
                af[rt] = frag_ld(As[cur], rt * 16 + (lane & 15), kch);
            #pragma unroll
            for (int ct = 0; ct < 4; ct++)
                bf[ct] = frag_ld(Bs[cur], w * 64 + ct * 16 + (lane & 15), kch);
            #pragma unroll
            for (int rt = 0; rt < 4; rt++)
                #pragma unroll
                for (int ct = 0; ct < 4; ct++)
                    acc[rt][ct] = __builtin_amdgcn_mfma_f32_16x16x32_bf16(
                        af[rt], bf[ct], acc[rt][ct], 0, 0, 0);
        }
        asm volatile("s_waitcnt lgkmcnt(0)" ::: "memory");     // ds_reads done before reuse
        __builtin_amdgcn_sched_barrier(0);
        __builtin_amdgcn_s_barrier();
        __builtin_amdgcn_sched_barrier(0);
    }

    // epilogue: C/D layout col=lane&15, row=(lane>>4)*4+reg  [m89-verified]
    const int rsub = (lane >> 4) * 4;
    #pragma unroll
    for (int rt = 0; rt < 4; rt++) {
        if constexpr (MODE == 0) {
            const int bt = a0 + rt * 16 + rsub;          // 4 consecutive bt (regs 0..3)
            const int bb = bt / NT, tt = bt - bb * NT;   // bt%4==0 -> never straddles b
            #pragma unroll
            for (int ct = 0; ct < 4; ct++) {
                const int co = w * 64 + ct * 16 + (lane & 15);
                const float bv = bias[co];
                f32x4 v = acc[rt][ct];
                uint2 st = { pk2(v[0] + bv, v[1] + bv), pk2(v[2] + bv, v[3] + bv) };
                *(uint2*)&out[(size_t)(bb * 256 + co) * NT + tt] = st;
            }
        } else {
            const int g = a0 + rt * 16 + rsub;           // 4 consecutive gates
            const float4 b4 = *(const float4*)&bias[g];
            #pragma unroll
            for (int ct = 0; ct < 4; ct++) {
                const int btj = b0 + w * 64 + ct * 16 + (lane & 15);
                f32x4 v = acc[rt][ct];
                uint2 st = { pk2(v[0] + b4.x, v[1] + b4.y), pk2(v[2] + b4.z, v[3] + b4.w) };
                *(uint2*)&out[(size_t)btj * NT + g] = st;
            }
        }
    }
}

// ---------- K4: MFMA-based fused GRU1+GRU2 scan ----------
// 16 blocks x 512 threads (8 waves); block owns batches b0..b0+15.
// Per phase: D[384 n][16 b] = W(A-frag, in regs) x h(B-frag, LDS) via mfma 16x16x32;
// D -> LDS (stride 388), gates by static lanes (h-state in gate-lane regs).
// Phase A: rows 0-191 = w_ih1 h-part (gx), 192-383 = w_hh1 (gh), B=h1 for all.
// Phase B: rows 0-191 = w_ih2 (gx2, B=h1'), 192-383 = w_hh2 (gh2, B=h2).
__global__ __launch_bounds__(512) void k_scan_mfma(const uint16_t* __restrict__ g1b,
                                                   const float* __restrict__ w_ih1,
                                                   const float* __restrict__ w_hh1,
                                                   const float* __restrict__ b_hh1,
                                                   const float* __restrict__ w_ih2,
                                                   const float* __restrict__ w_hh2,
                                                   const float* __restrict__ b_ih2,
                                                   const float* __restrict__ b_hh2,
                                                   float* __restrict__ o2)
{
    __shared__ alignas(16) uint16_t tileH1[16 * 72];   // bf16 h1, row stride 72
    __shared__ alignas(16) uint16_t tileH2[16 * 72];   // bf16 h2
    __shared__ alignas(16) float    LDSd[16 * 388];    // D[n][b] -> [b][388]

    const int tid  = threadIdx.x;
    const int w    = tid >> 6;          // wave 0..7
    const int lane = tid & 63;
    const int g    = lane >> 4;         // 0..3
    const int b    = lane & 15;         // local batch row
    const int b0   = blockIdx.x * 16;
    const int bg   = b0 + b;            // global batch row
    const int nw   = w * 48;            // wave's n-slice base
    const int i0   = 2 * (w * 4 + g);   // gate pair owned by this lane

    // --- load weight A-fragments into registers (static across all steps) ---
    short8v wa[3][2], wb[3][2];
    #pragma unroll
    for (int tau = 0; tau < 3; tau++) {
        #pragma unroll
        for (int ks = 0; ks < 2; ks++) {
            const int n  = nw + tau * 16 + b;
            const int k0 = (ks * 4 + g) * 8;
            const float *pa, *pb;
            if (n < 192) { pa = w_ih1 + n * 256 + 192 + k0; pb = w_ih2 + n * 64 + k0; }
            else         { pa = w_hh1 + (n - 192) * 64 + k0; pb = w_hh2 + (n - 192) * 64 + k0; }
            wa[tau][ks] = pack8(pa);
            wb[tau][ks] = pack8(pb);
        }
    }
    // --- gate-lane bias preloads (for gates i0, i0+1) ---
    float2 bh1c[3], bi2c[3], bh2c[3];
    #pragma unroll
    for (int c = 0; c < 3; c++) {
        bh1c[c] = *(const float2*)(b_hh1 + c * 64 + i0);
        bi2c[c] = *(const float2*)(b_ih2 + c * 64 + i0);
        bh2c[c] = *(const float2*)(b_hh2 + c * 64 + i0);
    }

    // --- zero h tiles ---
    for (int idx = tid; idx < 16 * 72 / 2 * 2; idx += 512)  // 1152 u16 per tile
        { tileH1[idx] = 0; tileH2[idx] = 0; }
    wg_barrier();

    // h state in gate-lane registers
    float h1o0 = 0.f, h1o1 = 0.f, h2o0 = 0.f, h2o1 = 0.f;

    const uint32_t* g1b32 = (const uint32_t*)g1b;
    // prefetch pre for j=0 (3 u32: components r,z,n for gates i0,i0+1)
    uint32_t pc0, pc1, pc2;
    {
        const size_t base = ((size_t)bg * 256 + 0) * 96 + (i0 >> 1);
        pc0 = g1b32[base]; pc1 = g1b32[base + 32]; pc2 = g1b32[base + 64];
    }

    for (int j = 0; j < 256; ++j) {
        // prefetch pre for j+1
        uint32_t pn0, pn1, pn2;
        {
            const int jn = (j + 1 < 256) ? j + 1 : 255;
            const size_t base = ((size_t)bg * 256 + jn) * 96 + (i0 >> 1);
            pn0 = g1b32[base]; pn1 = g1b32[base + 32]; pn2 = g1b32[base + 64];
        }

        // ---------- phase A: GEMM (all waves B = tileH1) ----------
        {
            f32x4 acc[3] = {(f32x4){0,0,0,0}, (f32x4){0,0,0,0}, (f32x4){0,0,0,0}};
            #pragma unroll
            for (int ks = 0; ks < 2; ks++) {
                const short8v bf = *(const short8v*)(tileH1 + b * 72 + (ks * 4 + g) * 8);
                #pragma unroll
                for (int tau = 0; tau < 3; tau++)
                    acc[tau] = __builtin_amdgcn_mfma_f32_16x16x32_bf16(
                        wa[tau][ks], bf, acc[tau], 0, 0, 0);
            }
            #pragma unroll
            for (int tau = 0; tau < 3; tau++)
                *(float4*)&LDSd[b * 388 + nw + tau * 16 + g * 4] = *(float4*)&acc[tau];
        }
        wg_barrier();   // barrier 1: D visible

        // ---------- gates A (each lane: gates (b, i0), (b, i0+1)) ----------
        {
            float2 dgr = *(const float2*)&LDSd[b * 388 +   0 + i0];
            float2 dgz = *(const float2*)&LDSd[b * 388 +  64 + i0];
            float2 dgn = *(const float2*)&LDSd[b * 388 + 128 + i0];
            float2 dhr = *(const float2*)&LDSd[b * 388 + 192 + i0];
            float2 dhz = *(const float2*)&LDSd[b * 388 + 256 + i0];
            float2 dhn = *(const float2*)&LDSd[b * 388 + 320 + i0];
            float pr0 = bf2f((uint16_t)pc0), pr1 = bf2f((uint16_t)(pc0 >> 16));
            float pz0 = bf2f((uint16_t)pc1), pz1 = bf2f((uint16_t)(pc1 >> 16));
            float pn_0 = bf2f((uint16_t)pc2), pn_1 = bf2f((uint16_t)(pc2 >> 16));

            float r0 = sigmoidf_((pr0 + dgr.x) + (dhr.x + bh1c[0].x));
            float z0 = sigmoidf_((pz0 + dgz.x) + (dhz.x + bh1c[1].x));
            float n0 = tanhf_((pn_0 + dgn.x) + r0 * (dhn.x + bh1c[2].x));
            float r1 = sigmoidf_((pr1 + dgr.y) + (dhr.y + bh1c[0].y));
            float z1 = sigmoidf_((pz1 + dgz.y) + (dhz.y + bh1c[1].y));
            float n1 = tanhf_((pn_1 + dgn.y) + r1 * (dhn.y + bh1c[2].y));
            h1o0 = (1.f - z0) * n0 + z0 * h1o0;
            h1o1 = (1.f - z1) * n1 + z1 * h1o1;
            *(uint32_t*)(tileH1 + b * 72 + i0) = pk2(h1o0, h1o1);
        }
        wg_barrier();   // barrier 2: h1' visible, gate-A LDSd reads drained

        // ---------- phase B: GEMM (waves 0-3: B=h1' ; waves 4-7: B=h2) ----------
        {
            const uint16_t* tH = (w < 4) ? tileH1 : tileH2;
            f32x4 acc[3] = {(f32x4){0,0,0,0}, (f32x4){0,0,0,0}, (f32x4){0,0,0,0}};
            #pragma unroll
            for (int ks = 0; ks < 2; ks++) {
                const short8v bf = *(const short8v*)(tH + b * 72 + (ks * 4 + g) * 8);
                #pragma unroll
                for (int tau = 0; tau < 3; tau++)
                    acc[tau] = __builtin_amdgcn_mfma_f32_16x16x32_bf16(
                        wb[tau][ks], bf, acc[tau], 0, 0, 0);
            }
            #pragma unroll
            for (int tau = 0; tau < 3; tau++)
                *(float4*)&LDSd[b * 388 + nw + tau * 16 + g * 4] = *(float4*)&acc[tau];
        }
        wg_barrier();   // barrier 3: D visible

        // ---------- gates B ----------
        {
            float2 dgr = *(const float2*)&LDSd[b * 388 +   0 + i0];
            float2 dgz = *(const float2*)&LDSd[b * 388 +  64 + i0];
            float2 dgn = *(const float2*)&LDSd[b * 388 + 128 + i0];
            float2 dhr = *(const float2*)&LDSd[b * 388 + 192 + i0];
            float2 dhz = *(const float2*)&LDSd[b * 388 + 256 + i0];
            float2 dhn = *(const float2*)&LDSd[b * 388 + 320 + i0];

            float r0 = sigmoidf_((dgr.x + bi2c[0].x) + (dhr.x + bh2c[0].x));
            float z0 = sigmoidf_((dgz.x + bi2c[1].x) + (dhz.x + bh2c[1].x));
            float n0 = tanhf_((dgn.x + bi2c[2].x) + r0 * (dhn.x + bh2c[2].x));
            float r1 = sigmoidf_((dgr.y + bi2c[0].y) + (dhr.y + bh2c[0].y));
            float z1 = sigmoidf_((dgz.y + bi2c[1].y) + (dhz.y + bh2c[1].y));
            float n1 = tanhf_((dgn.y + bi2c[2].y) + r1 * (dhn.y + bh2c[2].y));
            h2o0 = (1.f - z0) * n0 + z0 * h2o0;
            h2o1 = (1.f - z1) * n1 + z1 * h2o1;
            *(uint32_t*)(tileH2 + b * 72 + i0) = pk2(h2o0, h2o1);
            *(float2*)&o2[((size_t)bg * 256 + j) * 64 + i0] = make_float2(h2o0, h2o1);
        }
        wg_barrier();   // barrier 4: h2' visible, gate-B LDSd reads drained

        pc0 = pn0; pc1 = pn1; pc2 = pn2;
    }
}

// ---------- K5: FC head  out = relu(o2 @ fc1_w.T + b1) @ fc2_w.T + b2 ----------
__global__ __launch_bounds__(256) void k_fc(const float* __restrict__ o2,
                                            const float* __restrict__ fc1_w,
                                            const float* __restrict__ fc1_b,
                                            const float* __restrict__ fc2_w,
                                            const float* __restrict__ fc2_b,
                                            float* __restrict__ out)
{
    const int lane = threadIdx.x & 63;
    const int wid  = blockIdx.x * 4 + (threadIdx.x >> 6);   // 0..2047

    float w1[64], w2[64];
    {
        const float4* p = (const float4*)(fc1_w + lane * 64);
        #pragma unroll
        for (int i = 0; i < 16; i++) {
            float4 a = p[i]; w1[4*i]=a.x; w1[4*i+1]=a.y; w1[4*i+2]=a.z; w1[4*i+3]=a.w;
        }
    }
    const float b1v = fc1_b[lane];
    float b2v = 0.f;
    if (lane < NOUT) {
        const float4* p = (const float4*)(fc2_w + lane * 64);
        #pragma unroll
        for (int i = 0; i < 16; i++) {
            float4 a = p[i]; w2[4*i]=a.x; w2[4*i+1]=a.y; w2[4*i+2]=a.z; w2[4*i+3]=a.w;
        }
        b2v = fc2_b[lane];
    } else {
        #pragma unroll
        for (int i = 0; i < 64; i++) w2[i] = 0.f;
    }

    for (int r = wid; r < NB * NC; r += 2048) {
        float v = o2[(size_t)r * 64 + lane];
        float y = b1v;
        #pragma unroll
        for (int m = 0; m < 64; m++) y = fmaf(lane_bcast(v, m), w1[m], y);
        y = fmaxf(y, 0.f);
        float o = b2v;
        #pragma unroll
        for (int m = 0; m < 64; m++) o = fmaf(lane_bcast(y, m), w2[m], o);
        if (lane < NOUT) out[(size_t)r * NOUT + lane] = o;
    }
}

// ---------- launch ----------
extern "C" void kernel_launch(void* const* d_in, const int* in_sizes, int n_in,
                              void* d_out, int out_size, void* d_ws, size_t ws_size,
                              hipStream_t stream)
{
    (void)in_sizes; (void)n_in; (void)out_size;
    const float* x       = (const float*)d_in[0];
    const float* conv1_w = (const float*)d_in[1];
    const float* conv1_b = (const float*)d_in[2];
    const float* conv2_w = (const float*)d_in[3];
    const float* conv2_b = (const float*)d_in[4];
    const float* w_ih1   = (const float*)d_in[5];
    const float* w_hh1   = (const float*)d_in[6];
    const float* b_ih1   = (const float*)d_in[7];
    const float* b_hh1   = (const float*)d_in[8];
    const float* w_ih2   = (const float*)d_in[9];
    const float* w_hh2   = (const float*)d_in[10];
    const float* b_ih2   = (const float*)d_in[11];
    const float* b_hh2   = (const float*)d_in[12];
    const float* fc1_w   = (const float*)d_in[13];
    const float* fc1_b   = (const float*)d_in[14];
    const float* fc2_w   = (const float*)d_in[15];
    const float* fc2_b   = (const float*)d_in[16];
    float* out = (float*)d_out;

    // workspace layout (total 219,041,792 B ~ 209 MiB)
    if (ws_size < 219041792ull) return;  // fail "incorrect", not a fault
    char* ws = (char*)d_ws;
    uint16_t* h1      = (uint16_t*)(ws);               // 150,994,944 B  bf16 [bt][y*256+ci]
    uint16_t* featsb  = (uint16_t*)(ws + 150994944);   //  25,165,824 B  bf16 [b*256+co][192]
    uint16_t* g1b     = (uint16_t*)(ws + 176160768);   //  25,165,824 B  bf16 [b*256+j][192]
    float*    o2      = (float*)   (ws + 201326592);   //  16,777,216 B  f32  [b*256+j][64]
    uint16_t* w2b     = (uint16_t*)(ws + 218103808);   //     786,432 B  bf16 [co][y*256+ci]
    uint16_t* w_ih1b  = (uint16_t*)(ws + 218890240);   //      98,304 B  bf16 [g][256]
    uint16_t* w1b     = (uint16_t*)(ws + 218988544);   //      53,248 B  bf16 [co][104] k-pad

    k_cvtw1<<<dim3(52),  256, 0, stream>>>(conv1_w, w1b);
    k_cvtw2<<<dim3(768), 256, 0, stream>>>(conv2_w, w2b);
    k_cvt  <<<dim3(96),  256, 0, stream>>>(w_ih1, w_ih1b, 49152);
    k_conv1_mfma<<<dim3(12, 256), 256, 0, stream>>>(x, w1b, conv1_b, h1);
    // conv2: M=49152 bt, N=256 co (one B-tile), K=1536 (24 steps)
    k_gemm<0><<<dim3(768, 1), 256, 0, stream>>>(h1, w2b, conv2_b, featsb, 24, K2, K2);
    // g1pre: M=192 g, N=65536 btj, K=192 (3 steps)
    k_gemm<1><<<dim3(3, 256), 256, 0, stream>>>(w_ih1b, featsb, b_ih1, g1b, 3, 256, NT);
    k_scan_mfma<<<dim3(16), 512, 0, stream>>>(g1b, w_ih1, w_hh1, b_hh1,
                                              w_ih2, w_hh2, b_ih2, b_hh2, o2);
    k_fc<<<dim3(512), 256, 0, stream>>>(o2, fc1_w, fc1_b, fc2_w, fc2_b, out);
}

// Round 5
// 618.858 us; speedup vs baseline: 1.2276x; 1.2276x over previous
//
#include <hip/hip_runtime.h>
#include <stdint.h>

// Problem constants
#define NB   256     // batch
#define NT   192     // frames
#define NH   64      // hidden
#define NC   256     // conv channels / scan steps
#define NOUT 28
#define K2   1536    // conv2 reduction = 256ci * 6y (re-keyed as y*256+ci)

typedef __attribute__((ext_vector_type(8))) short short8v;  // 8 bf16 (4 VGPR)
typedef __attribute__((ext_vector_type(4))) float f32x4;    // MFMA acc

// ---------- helpers ----------
__device__ __forceinline__ float lane_bcast(float v, int m) {
    return __int_as_float(__builtin_amdgcn_readlane(__float_as_int(v), m));
}
__device__ __forceinline__ uint16_t f2bf(float f) {          // RNE f32->bf16
    uint32_t u = __float_as_uint(f);
    return (uint16_t)((u + 0x7fffu + ((u >> 16) & 1u)) >> 16);
}
__device__ __forceinline__ uint32_t pk2(float a, float b) {
    return (uint32_t)f2bf(a) | ((uint32_t)f2bf(b) << 16);
}
__device__ __forceinline__ float bf2f(uint16_t u) {
    return __uint_as_float((uint32_t)u << 16);
}
__device__ __forceinline__ float sigmoidf_(float x) { return 1.f / (1.f + __expf(-x)); }
__device__ __forceinline__ float tanhf_(float x) {
    float a = fabsf(x);
    float e = __expf(2.f * a);          // inf for large a is fine: 2/(inf+1)=0
    float r = 1.f - 2.f / (e + 1.f);
    return (x < 0.f) ? -r : r;
}
// raw barrier: LDS-ordering only, does NOT drain vmcnt (keeps global prefetch alive)
__device__ __forceinline__ void wg_barrier() {
    asm volatile("s_waitcnt lgkmcnt(0)\n\ts_barrier" ::: "memory");
}
// async global->LDS, 16 B per lane; LDS dest is wave-uniform base + lane*16
__device__ __forceinline__ void gload_lds16(const uint16_t* g, uint16_t* l) {
    __builtin_amdgcn_global_load_lds(
        (const __attribute__((address_space(1))) uint32_t*)(const void*)g,
        (__attribute__((address_space(3))) uint32_t*)(void*)l, 16, 0, 0);
}
// read one MFMA operand fragment from a [rows][64] bf16 LDS tile, XOR-swizzled
__device__ __forceinline__ short8v frag_ld(const uint16_t* tile, int row, int kchunk) {
    const int kc = kchunk ^ (row & 7);
    return *(const short8v*)(tile + row * 64 + kc * 8);
}
// pack 8 consecutive f32 -> short8v (bf16)
__device__ __forceinline__ short8v pack8(const float* p) {
    float4 q0 = *(const float4*)p;
    float4 q1 = *(const float4*)(p + 4);
    union { short8v v; uint32_t u[4]; } r;
    r.u[0] = pk2(q0.x, q0.y); r.u[1] = pk2(q0.z, q0.w);
    r.u[2] = pk2(q1.x, q1.y); r.u[3] = pk2(q1.z, q1.w);
    return r.v;
}

// ---------- K0a: fp32 -> bf16 conversion (n even) ----------
__global__ __launch_bounds__(256) void k_cvt(const float* __restrict__ src,
                                             uint16_t* __restrict__ dst, int n)
{
    int i = blockIdx.x * 256 + threadIdx.x;      // converts 2 elems
    if (2 * i < n) {
        float2 v = *(const float2*)(src + 2 * i);
        ((uint32_t*)dst)[i] = pk2(v.x, v.y);
    }
}

// ---------- K0b: w1 (256,72) fp32 -> w1b_pad (256,104) bf16, k>=72 zero ----------
__global__ __launch_bounds__(256) void k_cvtw1(const float* __restrict__ w1,
                                               uint16_t* __restrict__ dst)
{
    int id = blockIdx.x * 256 + threadIdx.x;     // one u32 pair
    if (id < 256 * 52) {
        int co = id / 52, p = id - co * 52;
        uint32_t v = 0u;
        if (p < 36) {
            float2 q = *(const float2*)(w1 + co * 72 + 2 * p);
            v = pk2(q.x, q.y);
        }
        ((uint32_t*)dst)[id] = v;
    }
}

// ---------- K0c: w2 [co][ci*6+y] fp32 -> w2b [co][y*256+ci] bf16 ----------
__global__ __launch_bounds__(256) void k_cvtw2(const float* __restrict__ w2,
                                               uint16_t* __restrict__ dst)
{
    int id = blockIdx.x * 256 + threadIdx.x;     // one u32 pair
    if (id < 196608) {
        int co  = id / 768;
        int rem = id - co * 768;
        int y   = rem / 128;
        int cp  = rem - y * 128;
        int ci0 = cp * 2;
        float a = w2[(size_t)co * 1536 + ci0 * 6 + y];
        float b = w2[(size_t)co * 1536 + (ci0 + 1) * 6 + y];
        ((uint32_t*)dst)[id] = pk2(a, b);
    }
}

// ---------- K1: conv1 via implicit-GEMM MFMA ----------
// D[co][m=(lt,y)] = sum_{k=(ci,dt,dr,dw)} W[co][k] * P[m][k];  h1 relu'd, k-order y*256+ci
__global__ __launch_bounds__(256) void k_conv1_mfma(const float* __restrict__ x,
                                                    const uint16_t* __restrict__ w1b,
                                                    const float* __restrict__ b1,
                                                    uint16_t* __restrict__ h1)
{
    __shared__ alignas(16) uint16_t Wt[256 * 104];     // 53248 B (DMA, linear)
    __shared__ alignas(16) uint16_t Pt[96 * 100];      // 19200 B (constructed)
    __shared__ alignas(16) float patch[2 * 18 * 64];   //  9216 B [ci][tt][1+f]
    const int tid  = threadIdx.x;
    const int w    = tid >> 6;
    const int lane = tid & 63;
    const int tblk = blockIdx.x;                       // 0..11
    const int b    = blockIdx.y;                       // 0..255
    const int t0   = tblk * 16;

    // 1) issue W DMA: 3328 16B-chunks, 13 per lane
    #pragma unroll
    for (int i = 0; i < 13; i++) {
        const int cbase = i * 256 + w * 64;
        gload_lds16(w1b + (size_t)(cbase + lane) * 8, &Wt[cbase * 8]);
    }

    // 2) stage fp32 patch (frames t0-1 .. t0+16), zero-pad t boundary
    for (int idx = tid; idx < 2 * 18 * 63; idx += 256) {
        int ci  = idx / 1134;
        int rem = idx - ci * 1134;
        int tt  = rem / 63;
        int f   = rem - tt * 63;
        int gf  = t0 - 1 + tt;
        float v = 0.f;
        if (gf >= 0 && gf < NT) v = x[(size_t)b * 24192 + ci * 12096 + gf * 63 + f];
        patch[ci * 1152 + tt * 64 + 1 + f] = v;
    }
    __syncthreads();   // patch ready (also drains W DMA; fine, one-shot kernel)

    // 3) construct P[m][k]: m=lt*6+y, k=cd*12 + (dr*3+dw), cd=(ci,dt); rows stride 100
    for (int l = 0; l < 3; l++) {
        int idx = tid + l * 256;
        if (idx < 576) {
            int m  = idx / 6;
            int cd = idx - m * 6;
            int ci = cd / 3, dt = cd - ci * 3;
            int lt = m / 6,  y  = m - lt * 6;
            const float* pb = &patch[ci * 1152 + (lt + dt) * 64];
            uint2* dst = (uint2*)(Pt + m * 100 + cd * 12);   // 24B, 8B-aligned
            if (y == 0) {   // rows -3..0: dr<3 zero, dr=3 -> pb[1..3]
                dst[0] = (uint2){0u, 0u};
                dst[1] = (uint2){0u, 0u};
                dst[2] = (uint2){(uint32_t)f2bf(pb[1]) << 16, pk2(pb[2], pb[3])};
            } else {
                const float4* q = (const float4*)(pb + 12 * y - 8);
                float4 q0 = q[0], q1 = q[1], q2 = q[2];
                dst[0] = (uint2){pk2(q0.x, q0.y), pk2(q0.z, q0.w)};
                dst[1] = (uint2){pk2(q1.x, q1.y), pk2(q1.z, q1.w)};
                dst[2] = (uint2){pk2(q2.x, q2.y), pk2(q2.z, q2.w)};
            }
        }
    }
    // zero P k-pad 72..95 (both operands' pad zero => safe vs stale LDS)
    {
        int idx = tid;
        if (idx < 192) {
            int m = idx >> 1, half = idx & 1;
            uint2* dst = (uint2*)(Pt + m * 100 + 72 + half * 12);
            dst[0] = (uint2){0u, 0u};
            dst[1] = (uint2){0u, 0u};
            dst[2] = (uint2){0u, 0u};
        }
    }
    wg_barrier();      // P writes visible (W already drained)

    // 4) GEMM: wave w -> co tiles w*4..w*4+3 (64 co) x all 6 m-tiles, 3 K-steps
    f32x4 acc[4][6];
    #pragma unroll
    for (int i = 0; i < 4; i++)
        #pragma unroll
        for (int j = 0; j < 6; j++) acc[i][j] = (f32x4){0.f, 0.f, 0.f, 0.f};

    #pragma unroll
    for (int kstep = 0; kstep < 3; kstep++) {
        const int kch = kstep * 4 + (lane >> 4);       // chunk 0..11
        short8v wf[4], pf[6];
        #pragma unroll
        for (int at = 0; at < 4; at++)
            wf[at] = *(const short8v*)(Wt + ((w * 4 + at) * 16 + (lane & 15)) * 104 + kch * 8);
        #pragma unroll
        for (int mt = 0; mt < 6; mt++)
            pf[mt] = *(const short8v*)(Pt + (mt * 16 + (lane & 15)) * 100 + kch * 8);
        #pragma unroll
        for (int at = 0; at < 4; at++)
            #pragma unroll
            for (int mt = 0; mt < 6; mt++)
                acc[at][mt] = __builtin_amdgcn_mfma_f32_16x16x32_bf16(
                    wf[at], pf[mt], acc[at][mt], 0, 0, 0);
    }

    // 5) epilogue: D layout col(lane&15)=m, row((lane>>4)*4+reg)=co; relu; h1 k=y*256+ci
    #pragma unroll
    for (int mt = 0; mt < 6; mt++) {
        const int m  = mt * 16 + (lane & 15);
        const int lt = m / 6, y = m - lt * 6;
        uint16_t* rowp = h1 + (size_t)(b * NT + t0 + lt) * K2 + y * 256;
        #pragma unroll
        for (int at = 0; at < 4; at++) {
            const int co0 = (w * 4 + at) * 16 + (lane >> 4) * 4;
            float4 b4 = *(const float4*)&b1[co0];
            f32x4 v = acc[at][mt];
            float r0 = fmaxf(v[0] + b4.x, 0.f), r1 = fmaxf(v[1] + b4.y, 0.f);
            float r2 = fmaxf(v[2] + b4.z, 0.f), r3 = fmaxf(v[3] + b4.w, 0.f);
            *(uint2*)(rowp + co0) = (uint2){pk2(r0, r1), pk2(r2, r3)};
        }
    }
}

// ---------- K2: unified bf16 MFMA GEMM ----------
// C[arow][bcol] = sum_k A[arow][k] * B[bcol][k]  (both operands [entity][k] bf16)
// MODE 0 (conv2): A=h1[bt][1536], B=w2b[co][1536]; out=featsb[(b*256+co)][t] bf16 +b2[co]
// MODE 1 (g1pre): A=w_ih1b[g][256], B=featsb[btj][192]; out=g1b[btj][g] bf16 +b_ih1[g]
template<int MODE>
__global__ __launch_bounds__(256) void k_gemm(const uint16_t* __restrict__ A,
                                              const uint16_t* __restrict__ B,
                                              const float* __restrict__ bias,
                                              uint16_t* __restrict__ out,
                                              int kSteps, int lda, int ldb)
{
    __shared__ alignas(16) uint16_t As[2][64 * 64];     // 16 KB
    __shared__ alignas(16) uint16_t Bs[2][256 * 64];    // 64 KB
    const int tid  = threadIdx.x;
    const int w    = tid >> 6;
    const int lane = tid & 63;
    const int a0   = blockIdx.x * 64;
    const int b0   = blockIdx.y * 256;

    f32x4 acc[4][4];
    #pragma unroll
    for (int i = 0; i < 4; i++)
        #pragma unroll
        for (int j = 0; j < 4; j++) acc[i][j] = (f32x4){0.f, 0.f, 0.f, 0.f};

    auto stage = [&](int buf, int k0) {
        #pragma unroll
        for (int i = 0; i < 2; i++) {                    // A: 512 chunks, 2 instr/wave
            int c   = w * 128 + i * 64 + lane;
            int row = c >> 3;
            int kc  = (c & 7) ^ (row & 7);               // inverse swizzle on SOURCE
            gload_lds16(A + (size_t)(a0 + row) * lda + k0 + kc * 8,
                        &As[buf][(w * 128 + i * 64) * 8]);
        }
        #pragma unroll
        for (int i = 0; i < 8; i++) {                    // B: 2048 chunks, 8 instr/wave
            int c   = w * 512 + i * 64 + lane;
            int row = c >> 3;
            int kc  = (c & 7) ^ (row & 7);
            gload_lds16(B + (size_t)(b0 + row) * ldb + k0 + kc * 8,
                        &Bs[buf][(w * 512 + i * 64) * 8]);
        }
    };

    stage(0, 0);
    for (int t = 0; t < kSteps; ++t) {
        const int cur = t & 1;
        if (t + 1 < kSteps) {
            stage(cur ^ 1, (t + 1) * 64);
            asm volatile("s_waitcnt vmcnt(10)" ::: "memory");  // cur's 10 done, next 10 in flight
        } else {
            asm volatile("s_waitcnt vmcnt(0)" ::: "memory");
        }
        __builtin_amdgcn_sched_barrier(0);
        __builtin_amdgcn_s_barrier();
        __builtin_amdgcn_sched_barrier(0);
        #pragma unroll
        for (int ks = 0; ks < 2; ++ks) {
            short8v af[4], bf[4];
            const int kch = ks * 4 + (lane >> 4);
            #pragma unroll
            for (int rt = 0; rt < 4; rt++)
                af[rt] = frag_ld(As[cur], rt * 16 + (lane & 15), kch);
            #pragma unroll
            for (int ct = 0; ct < 4; ct++)
                bf[ct] = frag_ld(Bs[cur], w * 64 + ct * 16 + (lane & 15), kch);
            #pragma unroll
            for (int rt = 0; rt < 4; rt++)
                #pragma unroll
                for (int ct = 0; ct < 4; ct++)
                    acc[rt][ct] = __builtin_amdgcn_mfma_f32_16x16x32_bf16(
                        af[rt], bf[ct], acc[rt][ct], 0, 0, 0);
        }
        asm volatile("s_waitcnt lgkmcnt(0)" ::: "memory");     // ds_reads done before reuse
        __builtin_amdgcn_sched_barrier(0);
        __builtin_amdgcn_s_barrier();
        __builtin_amdgcn_sched_barrier(0);
    }

    // epilogue: C/D layout col=lane&15, row=(lane>>4)*4+reg  [m89-verified]
    const int rsub = (lane >> 4) * 4;
    #pragma unroll
    for (int rt = 0; rt < 4; rt++) {
        if constexpr (MODE == 0) {
            const int bt = a0 + rt * 16 + rsub;          // 4 consecutive bt (regs 0..3)
            const int bb = bt / NT, tt = bt - bb * NT;   // bt%4==0 -> never straddles b
            #pragma unroll
            for (int ct = 0; ct < 4; ct++) {
                const int co = w * 64 + ct * 16 + (lane & 15);
                const float bv = bias[co];
                f32x4 v = acc[rt][ct];
                uint2 st = { pk2(v[0] + bv, v[1] + bv), pk2(v[2] + bv, v[3] + bv) };
                *(uint2*)&out[(size_t)(bb * 256 + co) * NT + tt] = st;
            }
        } else {
            const int g = a0 + rt * 16 + rsub;           // 4 consecutive gates
            const float4 b4 = *(const float4*)&bias[g];
            #pragma unroll
            for (int ct = 0; ct < 4; ct++) {
                const int btj = b0 + w * 64 + ct * 16 + (lane & 15);
                f32x4 v = acc[rt][ct];
                uint2 st = { pk2(v[0] + b4.x, v[1] + b4.y), pk2(v[2] + b4.z, v[3] + b4.w) };
                *(uint2*)&out[(size_t)btj * NT + g] = st;
            }
        }
    }
}

// ---------- K4: wave-specialized pipelined GRU1+GRU2 scan ----------
// 16 blocks x 8 waves; block owns batches b0..b0+15.
// Waves 0-3: GRU1 step j=slot.  Waves 4-7: GRU2 step j2=slot-1 (1-step pipeline).
// Wave q (=w&3) owns h-dims [q*16, q*16+16) with ALL 6 gate components as MFMA
// tiles (A=weights in regs, B=h from LDS) -> gates fully in-register, no D exchange.
// h tiles double-buffered by slot parity; ONE barrier per slot.
// Fragment conventions identical to validated k_gemm (A/B row=lane&15, chunk=lane>>4;
// D col=lane&15, row=(lane>>4)*4+reg).
__global__ __launch_bounds__(512) void k_scan_pipe(const uint16_t* __restrict__ g1b,
                                                   const float* __restrict__ w_ih1,
                                                   const float* __restrict__ w_hh1,
                                                   const float* __restrict__ b_hh1,
                                                   const float* __restrict__ w_ih2,
                                                   const float* __restrict__ w_hh2,
                                                   const float* __restrict__ b_ih2,
                                                   const float* __restrict__ b_hh2,
                                                   float* __restrict__ o2)
{
    __shared__ alignas(16) uint16_t H1[2][16 * 64];   // h1 by slot parity, XOR-swizzled
    __shared__ alignas(16) uint16_t H2[2][16 * 64];   // h2 by slot parity

    const int tid  = threadIdx.x;
    const int w    = tid >> 6;
    const int lane = tid & 63;
    const int g    = lane >> 4;          // 0..3 (k-chunk group / reg-row group)
    const int b    = lane & 15;          // local batch
    const int q    = w & 3;              // h-dim segment
    const bool g1w = (w < 4);
    const int bg   = blockIdx.x * 16 + b;
    const int i0   = q * 16 + g * 4;     // first of 4 h-dims owned by this lane

    // --- A-fragments (weights) in registers, static across all 256 steps ---
    short8v wf[6][2];
    #pragma unroll
    for (int c = 0; c < 6; c++) {
        const int rowc = (c % 3) * 64 + q * 16 + (lane & 15);
        #pragma unroll
        for (int ks = 0; ks < 2; ks++) {
            const int koff = ks * 32 + g * 8;
            const float* src;
            if (g1w) src = (c < 3) ? (w_ih1 + rowc * 256 + 192 + koff)
                                   : (w_hh1 + rowc * 64 + koff);
            else     src = (c < 3) ? (w_ih2 + rowc * 64 + koff)
                                   : (w_hh2 + rowc * 64 + koff);
            wf[c][ks] = pack8(src);
        }
    }
    // --- biases for owned dims: GRU1: bA=b_hh1 ; GRU2: bA=b_ih2, bB=b_hh2 ---
    float4 bA[3], bB[3];
    #pragma unroll
    for (int c = 0; c < 3; c++) {
        bA[c] = *(const float4*)((g1w ? b_hh1 : b_ih2) + c * 64 + i0);
        bB[c] = *(const float4*)((g1w ? b_hh1 : b_hh2) + c * 64 + i0);
    }

    // --- zero both parities of both h tiles ---
    {
        uint32_t* z1 = (uint32_t*)H1;
        uint32_t* z2 = (uint32_t*)H2;
        for (int idx = tid; idx < 1024; idx += 512) { z1[idx] = 0u; z2[idx] = 0u; }
    }
    __syncthreads();

    float hs0 = 0.f, hs1 = 0.f, hs2 = 0.f, hs3 = 0.f;   // own h-state (h1 or h2 dims)

    // prefetch GRU1 pre (g1b) for j=0
    uint2 pc[3];
    if (g1w) {
        const uint16_t* base = g1b + (size_t)(bg * 256) * 192 + i0;
        pc[0] = *(const uint2*)(base);
        pc[1] = *(const uint2*)(base + 64);
        pc[2] = *(const uint2*)(base + 128);
    }

    for (int slot = 0; slot <= 256; ++slot) {
        const int p = slot & 1;
        if (g1w) {
            if (slot < 256) {
                // prefetch pre for next step (vmem: survives the raw barrier)
                const int jn = (slot + 1 < 256) ? slot + 1 : 255;
                const uint16_t* nb = g1b + (size_t)(bg * 256 + jn) * 192 + i0;
                uint2 pn0 = *(const uint2*)(nb);
                uint2 pn1 = *(const uint2*)(nb + 64);
                uint2 pn2 = *(const uint2*)(nb + 128);

                // B-frag: h1(slot-1) from H1[p^1]
                const uint16_t* hrd = H1[p ^ 1] + b * 64;
                short8v f0 = *(const short8v*)(hrd + ((0 + g) ^ (b & 7)) * 8);
                short8v f1 = *(const short8v*)(hrd + ((4 + g) ^ (b & 7)) * 8);
                f32x4 a[6];
                #pragma unroll
                for (int c = 0; c < 6; c++) {
                    a[c] = __builtin_amdgcn_mfma_f32_16x16x32_bf16(
                        wf[c][0], f0, (f32x4){0.f, 0.f, 0.f, 0.f}, 0, 0, 0);
                    a[c] = __builtin_amdgcn_mfma_f32_16x16x32_bf16(
                        wf[c][1], f1, a[c], 0, 0, 0);
                }
                // pre unpack (b_ih1 + x-part already folded by g1pre)
                float pr[4], pz[4], pnn[4];
                pr[0]=bf2f((uint16_t)pc[0].x); pr[1]=bf2f((uint16_t)(pc[0].x>>16));
                pr[2]=bf2f((uint16_t)pc[0].y); pr[3]=bf2f((uint16_t)(pc[0].y>>16));
                pz[0]=bf2f((uint16_t)pc[1].x); pz[1]=bf2f((uint16_t)(pc[1].x>>16));
                pz[2]=bf2f((uint16_t)pc[1].y); pz[3]=bf2f((uint16_t)(pc[1].y>>16));
                pnn[0]=bf2f((uint16_t)pc[2].x); pnn[1]=bf2f((uint16_t)(pc[2].x>>16));
                pnn[2]=bf2f((uint16_t)pc[2].y); pnn[3]=bf2f((uint16_t)(pc[2].y>>16));

                float nh[4];
                const float* bAr = (const float*)&bA[0];
                const float* bAz = (const float*)&bA[1];
                const float* bAn = (const float*)&bA[2];
                float hsv[4] = {hs0, hs1, hs2, hs3};
                #pragma unroll
                for (int r = 0; r < 4; r++) {
                    float rr = sigmoidf_((pr[r] + a[0][r]) + (a[3][r] + bAr[r]));
                    float zz = sigmoidf_((pz[r] + a[1][r]) + (a[4][r] + bAz[r]));
                    float nn = tanhf_((pnn[r] + a[2][r]) + rr * (a[5][r] + bAn[r]));
                    nh[r] = (1.f - zz) * nn + zz * hsv[r];
                }
                hs0 = nh[0]; hs1 = nh[1]; hs2 = nh[2]; hs3 = nh[3];
                // write h1' to H1[p] (chunk cd swizzled; 8B aligned)
                const int cd = q * 2 + (g >> 1);
                *(uint2*)(H1[p] + b * 64 + ((cd) ^ (b & 7)) * 8 + (g & 1) * 4) =
                    (uint2){pk2(nh[0], nh[1]), pk2(nh[2], nh[3])};
                pc[0] = pn0; pc[1] = pn1; pc[2] = pn2;
            }
        } else {
            if (slot >= 1) {
                const int j2 = slot - 1;
                // B-frags: x = h1(j2) from H1[p^1]; h2(j2-1) from H2[p^1]
                const uint16_t* xr = H1[p ^ 1] + b * 64;
                const uint16_t* hr = H2[p ^ 1] + b * 64;
                short8v x0 = *(const short8v*)(xr + ((0 + g) ^ (b & 7)) * 8);
                short8v x1 = *(const short8v*)(xr + ((4 + g) ^ (b & 7)) * 8);
                short8v y0 = *(const short8v*)(hr + ((0 + g) ^ (b & 7)) * 8);
                short8v y1 = *(const short8v*)(hr + ((4 + g) ^ (b & 7)) * 8);
                f32x4 a[6];
                #pragma unroll
                for (int c = 0; c < 3; c++) {
                    a[c] = __builtin_amdgcn_mfma_f32_16x16x32_bf16(
                        wf[c][0], x0, (f32x4){0.f, 0.f, 0.f, 0.f}, 0, 0, 0);
                    a[c] = __builtin_amdgcn_mfma_f32_16x16x32_bf16(
                        wf[c][1], x1, a[c], 0, 0, 0);
                }
                #pragma unroll
                for (int c = 3; c < 6; c++) {
                    a[c] = __builtin_amdgcn_mfma_f32_16x16x32_bf16(
                        wf[c][0], y0, (f32x4){0.f, 0.f, 0.f, 0.f}, 0, 0, 0);
                    a[c] = __builtin_amdgcn_mfma_f32_16x16x32_bf16(
                        wf[c][1], y1, a[c], 0, 0, 0);
                }
                float nh[4];
                const float* biR = (const float*)&bA[0];
                const float* biZ = (const float*)&bA[1];
                const float* biN = (const float*)&bA[2];
                const float* bhR = (const float*)&bB[0];
                const float* bhZ = (const float*)&bB[1];
                const float* bhN = (const float*)&bB[2];
                float hsv[4] = {hs0, hs1, hs2, hs3};
                #pragma unroll
                for (int r = 0; r < 4; r++) {
                    float rr = sigmoidf_((a[0][r] + biR[r]) + (a[3][r] + bhR[r]));
                    float zz = sigmoidf_((a[1][r] + biZ[r]) + (a[4][r] + bhZ[r]));
                    float nn = tanhf_((a[2][r] + biN[r]) + rr * (a[5][r] + bhN[r]));
                    nh[r] = (1.f - zz) * nn + zz * hsv[r];
                }
                hs0 = nh[0]; hs1 = nh[1]; hs2 = nh[2]; hs3 = nh[3];
                const int cd = q * 2 + (g >> 1);
                *(uint2*)(H2[p] + b * 64 + ((cd) ^ (b & 7)) * 8 + (g & 1) * 4) =
                    (uint2){pk2(nh[0], nh[1]), pk2(nh[2], nh[3])};
                *(float4*)&o2[((size_t)bg * 256 + j2) * 64 + i0] =
                    make_float4(nh[0], nh[1], nh[2], nh[3]);
            }
        }
        wg_barrier();    // writes of parity p visible; reads of p^1 drained
    }
}

// ---------- K5: FC head  out = relu(o2 @ fc1_w.T + b1) @ fc2_w.T + b2 ----------
__global__ __launch_bounds__(256) void k_fc(const float* __restrict__ o2,
                                            const float* __restrict__ fc1_w,
                                            const float* __restrict__ fc1_b,
                                            const float* __restrict__ fc2_w,
                                            const float* __restrict__ fc2_b,
                                            float* __restrict__ out)
{
    const int lane = threadIdx.x & 63;
    const int wid  = blockIdx.x * 4 + (threadIdx.x >> 6);   // 0..2047

    float w1[64], w2[64];
    {
        const float4* p = (const float4*)(fc1_w + lane * 64);
        #pragma unroll
        for (int i = 0; i < 16; i++) {
            float4 a = p[i]; w1[4*i]=a.x; w1[4*i+1]=a.y; w1[4*i+2]=a.z; w1[4*i+3]=a.w;
        }
    }
    const float b1v = fc1_b[lane];
    float b2v = 0.f;
    if (lane < NOUT) {
        const float4* p = (const float4*)(fc2_w + lane * 64);
        #pragma unroll
        for (int i = 0; i < 16; i++) {
            float4 a = p[i]; w2[4*i]=a.x; w2[4*i+1]=a.y; w2[4*i+2]=a.z; w2[4*i+3]=a.w;
        }
        b2v = fc2_b[lane];
    } else {
        #pragma unroll
        for (int i = 0; i < 64; i++) w2[i] = 0.f;
    }

    for (int r = wid; r < NB * NC; r += 2048) {
        float v = o2[(size_t)r * 64 + lane];
        float y = b1v;
        #pragma unroll
        for (int m = 0; m < 64; m++) y = fmaf(lane_bcast(v, m), w1[m], y);
        y = fmaxf(y, 0.f);
        float o = b2v;
        #pragma unroll
        for (int m = 0; m < 64; m++) o = fmaf(lane_bcast(y, m), w2[m], o);
        if (lane < NOUT) out[(size_t)r * NOUT + lane] = o;
    }
}

// ---------- launch ----------
extern "C" void kernel_launch(void* const* d_in, const int* in_sizes, int n_in,
                              void* d_out, int out_size, void* d_ws, size_t ws_size,
                              hipStream_t stream)
{
    (void)in_sizes; (void)n_in; (void)out_size;
    const float* x       = (const float*)d_in[0];
    const float* conv1_w = (const float*)d_in[1];
    const float* conv1_b = (const float*)d_in[2];
    const float* conv2_w = (const float*)d_in[3];
    const float* conv2_b = (const float*)d_in[4];
    const float* w_ih1   = (const float*)d_in[5];
    const float* w_hh1   = (const float*)d_in[6];
    const float* b_ih1   = (const float*)d_in[7];
    const float* b_hh1   = (const float*)d_in[8];
    const float* w_ih2   = (const float*)d_in[9];
    const float* w_hh2   = (const float*)d_in[10];
    const float* b_ih2   = (const float*)d_in[11];
    const float* b_hh2   = (const float*)d_in[12];
    const float* fc1_w   = (const float*)d_in[13];
    const float* fc1_b   = (const float*)d_in[14];
    const float* fc2_w   = (const float*)d_in[15];
    const float* fc2_b   = (const float*)d_in[16];
    float* out = (float*)d_out;

    // workspace layout (total 219,041,792 B ~ 209 MiB)
    if (ws_size < 219041792ull) return;  // fail "incorrect", not a fault
    char* ws = (char*)d_ws;
    uint16_t* h1      = (uint16_t*)(ws);               // 150,994,944 B  bf16 [bt][y*256+ci]
    uint16_t* featsb  = (uint16_t*)(ws + 150994944);   //  25,165,824 B  bf16 [b*256+co][192]
    uint16_t* g1b     = (uint16_t*)(ws + 176160768);   //  25,165,824 B  bf16 [b*256+j][192]
    float*    o2      = (float*)   (ws + 201326592);   //  16,777,216 B  f32  [b*256+j][64]
    uint16_t* w2b     = (uint16_t*)(ws + 218103808);   //     786,432 B  bf16 [co][y*256+ci]
    uint16_t* w_ih1b  = (uint16_t*)(ws + 218890240);   //      98,304 B  bf16 [g][256]
    uint16_t* w1b     = (uint16_t*)(ws + 218988544);   //      53,248 B  bf16 [co][104] k-pad

    k_cvtw1<<<dim3(52),  256, 0, stream>>>(conv1_w, w1b);
    k_cvtw2<<<dim3(768), 256, 0, stream>>>(conv2_w, w2b);
    k_cvt  <<<dim3(96),  256, 0, stream>>>(w_ih1, w_ih1b, 49152);
    k_conv1_mfma<<<dim3(12, 256), 256, 0, stream>>>(x, w1b, conv1_b, h1);
    // conv2: M=49152 bt, N=256 co (one B-tile), K=1536 (24 steps)
    k_gemm<0><<<dim3(768, 1), 256, 0, stream>>>(h1, w2b, conv2_b, featsb, 24, K2, K2);
    // g1pre: M=192 g, N=65536 btj, K=192 (3 steps)
    k_gemm<1><<<dim3(3, 256), 256, 0, stream>>>(w_ih1b, featsb, b_ih1, g1b, 3, 256, NT);
    k_scan_pipe<<<dim3(16), 512, 0, stream>>>(g1b, w_ih1, w_hh1, b_hh1,
                                              w_ih2, w_hh2, b_ih2, b_hh2, o2);
    k_fc<<<dim3(512), 256, 0, stream>>>(o2, fc1_w, fc1_b, fc2_w, fc2_b, out);
}

// Round 6
// 614.813 us; speedup vs baseline: 1.2357x; 1.0066x over previous
//
#include <hip/hip_runtime.h>
#include <stdint.h>

// Problem constants
#define NB   256     // batch
#define NT   192     // frames
#define NH   64      // hidden
#define NC   256     // conv channels / scan steps
#define NOUT 28
#define K2   1536    // conv2 reduction = 256ci * 6y (re-keyed as y*256+ci)

typedef __attribute__((ext_vector_type(8))) short short8v;  // 8 bf16 (4 VGPR)
typedef __attribute__((ext_vector_type(4))) float f32x4;    // MFMA acc

// ---------- helpers ----------
__device__ __forceinline__ float lane_bcast(float v, int m) {
    return __int_as_float(__builtin_amdgcn_readlane(__float_as_int(v), m));
}
__device__ __forceinline__ uint16_t f2bf(float f) {          // RNE f32->bf16
    uint32_t u = __float_as_uint(f);
    return (uint16_t)((u + 0x7fffu + ((u >> 16) & 1u)) >> 16);
}
__device__ __forceinline__ uint32_t pk2(float a, float b) {
    return (uint32_t)f2bf(a) | ((uint32_t)f2bf(b) << 16);
}
__device__ __forceinline__ float bf2f(uint16_t u) {
    return __uint_as_float((uint32_t)u << 16);
}
__device__ __forceinline__ float sigmoidf_(float x) { return 1.f / (1.f + __expf(-x)); }
__device__ __forceinline__ float tanhf_(float x) {
    float a = fabsf(x);
    float e = __expf(2.f * a);          // inf for large a is fine: 2/(inf+1)=0
    float r = 1.f - 2.f / (e + 1.f);
    return (x < 0.f) ? -r : r;
}
// raw barrier: LDS-ordering only, does NOT drain vmcnt (keeps global prefetch alive)
__device__ __forceinline__ void wg_barrier() {
    asm volatile("s_waitcnt lgkmcnt(0)\n\ts_barrier" ::: "memory");
}
// async global->LDS, 16 B per lane; LDS dest is wave-uniform base + lane*16
__device__ __forceinline__ void gload_lds16(const uint16_t* g, uint16_t* l) {
    __builtin_amdgcn_global_load_lds(
        (const __attribute__((address_space(1))) uint32_t*)(const void*)g,
        (__attribute__((address_space(3))) uint32_t*)(void*)l, 16, 0, 0);
}
// read one MFMA operand fragment from a [rows][64] bf16 LDS tile, XOR-swizzled
__device__ __forceinline__ short8v frag_ld(const uint16_t* tile, int row, int kchunk) {
    const int kc = kchunk ^ (row & 7);
    return *(const short8v*)(tile + row * 64 + kc * 8);
}
// pack 8 consecutive f32 -> short8v (bf16)
__device__ __forceinline__ short8v pack8(const float* p) {
    float4 q0 = *(const float4*)p;
    float4 q1 = *(const float4*)(p + 4);
    union { short8v v; uint32_t u[4]; } r;
    r.u[0] = pk2(q0.x, q0.y); r.u[1] = pk2(q0.z, q0.w);
    r.u[2] = pk2(q1.x, q1.y); r.u[3] = pk2(q1.z, q1.w);
    return r.v;
}

// ---------- K0a: fp32 -> bf16 conversion (n even) ----------
__global__ __launch_bounds__(256) void k_cvt(const float* __restrict__ src,
                                             uint16_t* __restrict__ dst, int n)
{
    int i = blockIdx.x * 256 + threadIdx.x;      // converts 2 elems
    if (2 * i < n) {
        float2 v = *(const float2*)(src + 2 * i);
        ((uint32_t*)dst)[i] = pk2(v.x, v.y);
    }
}

// ---------- K0b: w1 (256,72) fp32 -> w1b_pad (256,104) bf16, k>=72 zero ----------
__global__ __launch_bounds__(256) void k_cvtw1(const float* __restrict__ w1,
                                               uint16_t* __restrict__ dst)
{
    int id = blockIdx.x * 256 + threadIdx.x;     // one u32 pair
    if (id < 256 * 52) {
        int co = id / 52, p = id - co * 52;
        uint32_t v = 0u;
        if (p < 36) {
            float2 q = *(const float2*)(w1 + co * 72 + 2 * p);
            v = pk2(q.x, q.y);
        }
        ((uint32_t*)dst)[id] = v;
    }
}

// ---------- K0c: w2 [co][ci*6+y] fp32 -> w2b [co][y*256+ci] bf16 ----------
__global__ __launch_bounds__(256) void k_cvtw2(const float* __restrict__ w2,
                                               uint16_t* __restrict__ dst)
{
    int id = blockIdx.x * 256 + threadIdx.x;     // one u32 pair
    if (id < 196608) {
        int co  = id / 768;
        int rem = id - co * 768;
        int y   = rem / 128;
        int cp  = rem - y * 128;
        int ci0 = cp * 2;
        float a = w2[(size_t)co * 1536 + ci0 * 6 + y];
        float b = w2[(size_t)co * 1536 + (ci0 + 1) * 6 + y];
        ((uint32_t*)dst)[id] = pk2(a, b);
    }
}

// ---------- K1: conv1 via implicit-GEMM MFMA ----------
// D[co][m=(lt,y)] = sum_{k=(ci,dt,dr,dw)} W[co][k] * P[m][k];  h1 relu'd, k-order y*256+ci
__global__ __launch_bounds__(256) void k_conv1_mfma(const float* __restrict__ x,
                                                    const uint16_t* __restrict__ w1b,
                                                    const float* __restrict__ b1,
                                                    uint16_t* __restrict__ h1)
{
    __shared__ alignas(16) uint16_t Wt[256 * 104];     // 53248 B (DMA, linear)
    __shared__ alignas(16) uint16_t Pt[96 * 100];      // 19200 B (constructed)
    __shared__ alignas(16) float patch[2 * 18 * 64];   //  9216 B [ci][tt][1+f]
    const int tid  = threadIdx.x;
    const int w    = tid >> 6;
    const int lane = tid & 63;
    const int tblk = blockIdx.x;                       // 0..11
    const int b    = blockIdx.y;                       // 0..255
    const int t0   = tblk * 16;

    // 1) issue W DMA: 3328 16B-chunks, 13 per lane
    #pragma unroll
    for (int i = 0; i < 13; i++) {
        const int cbase = i * 256 + w * 64;
        gload_lds16(w1b + (size_t)(cbase + lane) * 8, &Wt[cbase * 8]);
    }

    // 2) stage fp32 patch (frames t0-1 .. t0+16), zero-pad t boundary
    for (int idx = tid; idx < 2 * 18 * 63; idx += 256) {
        int ci  = idx / 1134;
        int rem = idx - ci * 1134;
        int tt  = rem / 63;
        int f   = rem - tt * 63;
        int gf  = t0 - 1 + tt;
        float v = 0.f;
        if (gf >= 0 && gf < NT) v = x[(size_t)b * 24192 + ci * 12096 + gf * 63 + f];
        patch[ci * 1152 + tt * 64 + 1 + f] = v;
    }
    __syncthreads();   // patch ready (also drains W DMA; fine, one-shot kernel)

    // 3) construct P[m][k]: m=lt*6+y, k=cd*12 + (dr*3+dw), cd=(ci,dt); rows stride 100
    for (int l = 0; l < 3; l++) {
        int idx = tid + l * 256;
        if (idx < 576) {
            int m  = idx / 6;
            int cd = idx - m * 6;
            int ci = cd / 3, dt = cd - ci * 3;
            int lt = m / 6,  y  = m - lt * 6;
            const float* pb = &patch[ci * 1152 + (lt + dt) * 64];
            uint2* dst = (uint2*)(Pt + m * 100 + cd * 12);   // 24B, 8B-aligned
            if (y == 0) {   // rows -3..0: dr<3 zero, dr=3 -> pb[1..3]
                dst[0] = (uint2){0u, 0u};
                dst[1] = (uint2){0u, 0u};
                dst[2] = (uint2){(uint32_t)f2bf(pb[1]) << 16, pk2(pb[2], pb[3])};
            } else {
                const float4* q = (const float4*)(pb + 12 * y - 8);
                float4 q0 = q[0], q1 = q[1], q2 = q[2];
                dst[0] = (uint2){pk2(q0.x, q0.y), pk2(q0.z, q0.w)};
                dst[1] = (uint2){pk2(q1.x, q1.y), pk2(q1.z, q1.w)};
                dst[2] = (uint2){pk2(q2.x, q2.y), pk2(q2.z, q2.w)};
            }
        }
    }
    // zero P k-pad 72..95 (both operands' pad zero => safe vs stale LDS)
    {
        int idx = tid;
        if (idx < 192) {
            int m = idx >> 1, half = idx & 1;
            uint2* dst = (uint2*)(Pt + m * 100 + 72 + half * 12);
            dst[0] = (uint2){0u, 0u};
            dst[1] = (uint2){0u, 0u};
            dst[2] = (uint2){0u, 0u};
        }
    }
    wg_barrier();      // P writes visible (W already drained)

    // 4) GEMM: wave w -> co tiles w*4..w*4+3 (64 co) x all 6 m-tiles, 3 K-steps
    f32x4 acc[4][6];
    #pragma unroll
    for (int i = 0; i < 4; i++)
        #pragma unroll
        for (int j = 0; j < 6; j++) acc[i][j] = (f32x4){0.f, 0.f, 0.f, 0.f};

    #pragma unroll
    for (int kstep = 0; kstep < 3; kstep++) {
        const int kch = kstep * 4 + (lane >> 4);       // chunk 0..11
        short8v wf[4], pf[6];
        #pragma unroll
        for (int at = 0; at < 4; at++)
            wf[at] = *(const short8v*)(Wt + ((w * 4 + at) * 16 + (lane & 15)) * 104 + kch * 8);
        #pragma unroll
        for (int mt = 0; mt < 6; mt++)
            pf[mt] = *(const short8v*)(Pt + (mt * 16 + (lane & 15)) * 100 + kch * 8);
        #pragma unroll
        for (int at = 0; at < 4; at++)
            #pragma unroll
            for (int mt = 0; mt < 6; mt++)
                acc[at][mt] = __builtin_amdgcn_mfma_f32_16x16x32_bf16(
                    wf[at], pf[mt], acc[at][mt], 0, 0, 0);
    }

    // 5) epilogue: D layout col(lane&15)=m, row((lane>>4)*4+reg)=co; relu; h1 k=y*256+ci
    #pragma unroll
    for (int mt = 0; mt < 6; mt++) {
        const int m  = mt * 16 + (lane & 15);
        const int lt = m / 6, y = m - lt * 6;
        uint16_t* rowp = h1 + (size_t)(b * NT + t0 + lt) * K2 + y * 256;
        #pragma unroll
        for (int at = 0; at < 4; at++) {
            const int co0 = (w * 4 + at) * 16 + (lane >> 4) * 4;
            float4 b4 = *(const float4*)&b1[co0];
            f32x4 v = acc[at][mt];
            float r0 = fmaxf(v[0] + b4.x, 0.f), r1 = fmaxf(v[1] + b4.y, 0.f);
            float r2 = fmaxf(v[2] + b4.z, 0.f), r3 = fmaxf(v[3] + b4.w, 0.f);
            *(uint2*)(rowp + co0) = (uint2){pk2(r0, r1), pk2(r2, r3)};
        }
    }
}

// ---------- K2: unified bf16 MFMA GEMM ----------
// C[arow][bcol] = sum_k A[arow][k] * B[bcol][k]  (both operands [entity][k] bf16)
// MODE 0 (conv2): A=h1[bt][1536], B=w2b[co][1536]; out=featsb[(b*256+co)][t] bf16 +b2[co]
// MODE 1 (g1pre): A=w_ih1b[g][256], B=featsb[btj][192]; out=g1b[btj][g] bf16 +b_ih1[g]
template<int MODE>
__global__ __launch_bounds__(256) void k_gemm(const uint16_t* __restrict__ A,
                                              const uint16_t* __restrict__ B,
                                              const float* __restrict__ bias,
                                              uint16_t* __restrict__ out,
                                              int kSteps, int lda, int ldb)
{
    __shared__ alignas(16) uint16_t As[2][64 * 64];     // 16 KB
    __shared__ alignas(16) uint16_t Bs[2][256 * 64];    // 64 KB
    const int tid  = threadIdx.x;
    const int w    = tid >> 6;
    const int lane = tid & 63;
    const int a0   = blockIdx.x * 64;
    const int b0   = blockIdx.y * 256;

    f32x4 acc[4][4];
    #pragma unroll
    for (int i = 0; i < 4; i++)
        #pragma unroll
        for (int j = 0; j < 4; j++) acc[i][j] = (f32x4){0.f, 0.f, 0.f, 0.f};

    auto stage = [&](int buf, int k0) {
        #pragma unroll
        for (int i = 0; i < 2; i++) {                    // A: 512 chunks, 2 instr/wave
            int c   = w * 128 + i * 64 + lane;
            int row = c >> 3;
            int kc  = (c & 7) ^ (row & 7);               // inverse swizzle on SOURCE
            gload_lds16(A + (size_t)(a0 + row) * lda + k0 + kc * 8,
                        &As[buf][(w * 128 + i * 64) * 8]);
        }
        #pragma unroll
        for (int i = 0; i < 8; i++) {                    // B: 2048 chunks, 8 instr/wave
            int c   = w * 512 + i * 64 + lane;
            int row = c >> 3;
            int kc  = (c & 7) ^ (row & 7);
            gload_lds16(B + (size_t)(b0 + row) * ldb + k0 + kc * 8,
                        &Bs[buf][(w * 512 + i * 64) * 8]);
        }
    };

    stage(0, 0);
    for (int t = 0; t < kSteps; ++t) {
        const int cur = t & 1;
        if (t + 1 < kSteps) {
            stage(cur ^ 1, (t + 1) * 64);
            asm volatile("s_waitcnt vmcnt(10)" ::: "memory");  // cur's 10 done, next 10 in flight
        } else {
            asm volatile("s_waitcnt vmcnt(0)" ::: "memory");
        }
        __builtin_amdgcn_sched_barrier(0);
        __builtin_amdgcn_s_barrier();
        __builtin_amdgcn_sched_barrier(0);
        #pragma unroll
        for (int ks = 0; ks < 2; ++ks) {
            short8v af[4], bf[4];
            const int kch = ks * 4 + (lane >> 4);
            #pragma unroll
            for (int rt = 0; rt < 4; rt++)
                af[rt] = frag_ld(As[cur], rt * 16 + (lane & 15), kch);
            #pragma unroll
            for (int ct = 0; ct < 4; ct++)
                bf[ct] = frag_ld(Bs[cur], w * 64 + ct * 16 + (lane & 15), kch);
            #pragma unroll
            for (int rt = 0; rt < 4; rt++)
                #pragma unroll
                for (int ct = 0; ct < 4; ct++)
                    acc[rt][ct] = __builtin_amdgcn_mfma_f32_16x16x32_bf16(
                        af[rt], bf[ct], acc[rt][ct], 0, 0, 0);
        }
        asm volatile("s_waitcnt lgkmcnt(0)" ::: "memory");     // ds_reads done before reuse
        __builtin_amdgcn_sched_barrier(0);
        __builtin_amdgcn_s_barrier();
        __builtin_amdgcn_sched_barrier(0);
    }

    // epilogue: C/D layout col=lane&15, row=(lane>>4)*4+reg  [m89-verified]
    const int rsub = (lane >> 4) * 4;
    #pragma unroll
    for (int rt = 0; rt < 4; rt++) {
        if constexpr (MODE == 0) {
            const int bt = a0 + rt * 16 + rsub;          // 4 consecutive bt (regs 0..3)
            const int bb = bt / NT, tt = bt - bb * NT;   // bt%4==0 -> never straddles b
            #pragma unroll
            for (int ct = 0; ct < 4; ct++) {
                const int co = w * 64 + ct * 16 + (lane & 15);
                const float bv = bias[co];
                f32x4 v = acc[rt][ct];
                uint2 st = { pk2(v[0] + bv, v[1] + bv), pk2(v[2] + bv, v[3] + bv) };
                *(uint2*)&out[(size_t)(bb * 256 + co) * NT + tt] = st;
            }
        } else {
            const int g = a0 + rt * 16 + rsub;           // 4 consecutive gates
            const float4 b4 = *(const float4*)&bias[g];
            #pragma unroll
            for (int ct = 0; ct < 4; ct++) {
                const int btj = b0 + w * 64 + ct * 16 + (lane & 15);
                f32x4 v = acc[rt][ct];
                uint2 st = { pk2(v[0] + b4.x, v[1] + b4.y), pk2(v[2] + b4.z, v[3] + b4.w) };
                *(uint2*)&out[(size_t)btj * NT + g] = st;
            }
        }
    }
}

// ---------- K4: wave-specialized pipelined GRU1+GRU2 scan, 4-deep prefetch ring ----
// 16 blocks x 8 waves; block owns batches b0..b0+15.
// Waves 0-3: GRU1 step j=slot.  Waves 4-7: GRU2 step j2=slot-1 (1-step pipeline).
// Wave q (=w&3) owns h-dims [q*16, q*16+16) with ALL 6 gate components as MFMA
// tiles -> gates fully in-register. h tiles double-buffered by slot parity;
// ONE barrier per slot. g1b pre-values prefetched 4 slots ahead in a named
// register ring (static indices via 4x-unrolled slot loop) so the HBM latency
// (~900cy) sits under ~4 slots of slack instead of stalling each slot.
__global__ __launch_bounds__(512) void k_scan_pipe(const uint16_t* __restrict__ g1b,
                                                   const float* __restrict__ w_ih1,
                                                   const float* __restrict__ w_hh1,
                                                   const float* __restrict__ b_hh1,
                                                   const float* __restrict__ w_ih2,
                                                   const float* __restrict__ w_hh2,
                                                   const float* __restrict__ b_ih2,
                                                   const float* __restrict__ b_hh2,
                                                   float* __restrict__ o2)
{
    __shared__ alignas(16) uint16_t H1[2][16 * 64];   // h1 by slot parity, XOR-swizzled
    __shared__ alignas(16) uint16_t H2[2][16 * 64];   // h2 by slot parity

    const int tid  = threadIdx.x;
    const int w    = tid >> 6;
    const int lane = tid & 63;
    const int g    = lane >> 4;          // 0..3 (k-chunk group / reg-row group)
    const int b    = lane & 15;          // local batch
    const int q    = w & 3;              // h-dim segment
    const bool g1w = (w < 4);
    const int bg   = blockIdx.x * 16 + b;
    const int i0   = q * 16 + g * 4;     // first of 4 h-dims owned by this lane

    // --- A-fragments (weights) in registers, static across all 256 steps ---
    short8v wf[6][2];
    #pragma unroll
    for (int c = 0; c < 6; c++) {
        const int rowc = (c % 3) * 64 + q * 16 + (lane & 15);
        #pragma unroll
        for (int ks = 0; ks < 2; ks++) {
            const int koff = ks * 32 + g * 8;
            const float* src;
            if (g1w) src = (c < 3) ? (w_ih1 + rowc * 256 + 192 + koff)
                                   : (w_hh1 + rowc * 64 + koff);
            else     src = (c < 3) ? (w_ih2 + rowc * 64 + koff)
                                   : (w_hh2 + rowc * 64 + koff);
            wf[c][ks] = pack8(src);
        }
    }
    // --- biases for owned dims: GRU1: bA=b_hh1 ; GRU2: bA=b_ih2, bB=b_hh2 ---
    float4 bA[3], bB[3];
    #pragma unroll
    for (int c = 0; c < 3; c++) {
        bA[c] = *(const float4*)((g1w ? b_hh1 : b_ih2) + c * 64 + i0);
        bB[c] = *(const float4*)((g1w ? b_hh1 : b_hh2) + c * 64 + i0);
    }

    // --- zero both parities of both h tiles ---
    {
        uint32_t* z1 = (uint32_t*)H1;
        uint32_t* z2 = (uint32_t*)H2;
        for (int idx = tid; idx < 1024; idx += 512) { z1[idx] = 0u; z2[idx] = 0u; }
    }
    __syncthreads();

    float hs0 = 0.f, hs1 = 0.f, hs2 = 0.f, hs3 = 0.f;   // own h-state (h1 or h2 dims)

    const uint16_t* gbase = g1b + (size_t)bg * 256 * 192 + i0;

    // GRU1 cell for slot j (parity par), pre-values P0/P1/P2 (r/z/n gate quads)
    auto gru1 = [&](int slot, int par, uint2 P0, uint2 P1, uint2 P2) {
        const uint16_t* hrd = H1[par ^ 1] + b * 64;
        short8v f0 = *(const short8v*)(hrd + ((0 + g) ^ (b & 7)) * 8);
        short8v f1 = *(const short8v*)(hrd + ((4 + g) ^ (b & 7)) * 8);
        f32x4 a[6];
        #pragma unroll
        for (int c = 0; c < 6; c++) {
            a[c] = __builtin_amdgcn_mfma_f32_16x16x32_bf16(
                wf[c][0], f0, (f32x4){0.f, 0.f, 0.f, 0.f}, 0, 0, 0);
            a[c] = __builtin_amdgcn_mfma_f32_16x16x32_bf16(
                wf[c][1], f1, a[c], 0, 0, 0);
        }
        float pr[4], pz[4], pnn[4];
        pr[0]=bf2f((uint16_t)P0.x);  pr[1]=bf2f((uint16_t)(P0.x>>16));
        pr[2]=bf2f((uint16_t)P0.y);  pr[3]=bf2f((uint16_t)(P0.y>>16));
        pz[0]=bf2f((uint16_t)P1.x);  pz[1]=bf2f((uint16_t)(P1.x>>16));
        pz[2]=bf2f((uint16_t)P1.y);  pz[3]=bf2f((uint16_t)(P1.y>>16));
        pnn[0]=bf2f((uint16_t)P2.x); pnn[1]=bf2f((uint16_t)(P2.x>>16));
        pnn[2]=bf2f((uint16_t)P2.y); pnn[3]=bf2f((uint16_t)(P2.y>>16));

        float nh[4];
        const float* bAr = (const float*)&bA[0];
        const float* bAz = (const float*)&bA[1];
        const float* bAn = (const float*)&bA[2];
        float hsv[4] = {hs0, hs1, hs2, hs3};
        #pragma unroll
        for (int r = 0; r < 4; r++) {
            float rr = sigmoidf_((pr[r] + a[0][r]) + (a[3][r] + bAr[r]));
            float zz = sigmoidf_((pz[r] + a[1][r]) + (a[4][r] + bAz[r]));
            float nn = tanhf_((pnn[r] + a[2][r]) + rr * (a[5][r] + bAn[r]));
            nh[r] = (1.f - zz) * nn + zz * hsv[r];
        }
        hs0 = nh[0]; hs1 = nh[1]; hs2 = nh[2]; hs3 = nh[3];
        const int cd = q * 2 + (g >> 1);
        *(uint2*)(H1[par] + b * 64 + ((cd) ^ (b & 7)) * 8 + (g & 1) * 4) =
            (uint2){pk2(nh[0], nh[1]), pk2(nh[2], nh[3])};
    };

    // GRU2 cell for slot (j2 = slot-1, parity par)
    auto gru2 = [&](int slot, int par) {
        const int j2 = slot - 1;
        const uint16_t* xr = H1[par ^ 1] + b * 64;
        const uint16_t* hr = H2[par ^ 1] + b * 64;
        short8v x0 = *(const short8v*)(xr + ((0 + g) ^ (b & 7)) * 8);
        short8v x1 = *(const short8v*)(xr + ((4 + g) ^ (b & 7)) * 8);
        short8v y0 = *(const short8v*)(hr + ((0 + g) ^ (b & 7)) * 8);
        short8v y1 = *(const short8v*)(hr + ((4 + g) ^ (b & 7)) * 8);
        f32x4 a[6];
        #pragma unroll
        for (int c = 0; c < 3; c++) {
            a[c] = __builtin_amdgcn_mfma_f32_16x16x32_bf16(
                wf[c][0], x0, (f32x4){0.f, 0.f, 0.f, 0.f}, 0, 0, 0);
            a[c] = __builtin_amdgcn_mfma_f32_16x16x32_bf16(
                wf[c][1], x1, a[c], 0, 0, 0);
        }
        #pragma unroll
        for (int c = 3; c < 6; c++) {
            a[c] = __builtin_amdgcn_mfma_f32_16x16x32_bf16(
                wf[c][0], y0, (f32x4){0.f, 0.f, 0.f, 0.f}, 0, 0, 0);
            a[c] = __builtin_amdgcn_mfma_f32_16x16x32_bf16(
                wf[c][1], y1, a[c], 0, 0, 0);
        }
        float nh[4];
        const float* biR = (const float*)&bA[0];
        const float* biZ = (const float*)&bA[1];
        const float* biN = (const float*)&bA[2];
        const float* bhR = (const float*)&bB[0];
        const float* bhZ = (const float*)&bB[1];
        const float* bhN = (const float*)&bB[2];
        float hsv[4] = {hs0, hs1, hs2, hs3};
        #pragma unroll
        for (int r = 0; r < 4; r++) {
            float rr = sigmoidf_((a[0][r] + biR[r]) + (a[3][r] + bhR[r]));
            float zz = sigmoidf_((a[1][r] + biZ[r]) + (a[4][r] + bhZ[r]));
            float nn = tanhf_((a[2][r] + biN[r]) + rr * (a[5][r] + bhN[r]));
            nh[r] = (1.f - zz) * nn + zz * hsv[r];
        }
        hs0 = nh[0]; hs1 = nh[1]; hs2 = nh[2]; hs3 = nh[3];
        const int cd = q * 2 + (g >> 1);
        *(uint2*)(H2[par] + b * 64 + ((cd) ^ (b & 7)) * 8 + (g & 1) * 4) =
            (uint2){pk2(nh[0], nh[1]), pk2(nh[2], nh[3])};
        *(float4*)&o2[((size_t)bg * 256 + j2) * 64 + i0] =
            make_float4(nh[0], nh[1], nh[2], nh[3]);
    };

    auto ld3 = [&](int j, uint2& A, uint2& B2, uint2& C) {
        const uint16_t* nb = gbase + (size_t)j * 192;
        A  = *(const uint2*)(nb);
        B2 = *(const uint2*)(nb + 64);
        C  = *(const uint2*)(nb + 128);
    };

    // prefetch ring: 4 named triples (slot s uses ring slot s&3)
    uint2 Ra0, Ra1, Ra2, Rb0, Rb1, Rb2, Rc0, Rc1, Rc2, Rd0, Rd1, Rd2;
    if (g1w) {
        ld3(0, Ra0, Ra1, Ra2); ld3(1, Rb0, Rb1, Rb2);
        ld3(2, Rc0, Rc1, Rc2); ld3(3, Rd0, Rd1, Rd2);
    }

    // slot 0 (GRU1 only, parity 0)
    if (g1w) { gru1(0, 0, Ra0, Ra1, Ra2); ld3(4, Ra0, Ra1, Ra2); }
    wg_barrier();

    for (int m = 0; m < 64; ++m) {
        const int s0 = 4 * m + 1;
        // sub-slot k=0: slot s0, parity 1, ring Rb
        if (g1w) {
            if (s0 < 256) {
                gru1(s0, 1, Rb0, Rb1, Rb2);
                if (s0 + 4 < 256) ld3(s0 + 4, Rb0, Rb1, Rb2);
            }
        } else gru2(s0, 1);
        wg_barrier();
        // sub-slot k=1: slot s0+1, parity 0, ring Rc
        if (g1w) {
            if (s0 + 1 < 256) {
                gru1(s0 + 1, 0, Rc0, Rc1, Rc2);
                if (s0 + 5 < 256) ld3(s0 + 5, Rc0, Rc1, Rc2);
            }
        } else gru2(s0 + 1, 0);
        wg_barrier();
        // sub-slot k=2: slot s0+2, parity 1, ring Rd
        if (g1w) {
            if (s0 + 2 < 256) {
                gru1(s0 + 2, 1, Rd0, Rd1, Rd2);
                if (s0 + 6 < 256) ld3(s0 + 6, Rd0, Rd1, Rd2);
            }
        } else gru2(s0 + 2, 1);
        wg_barrier();
        // sub-slot k=3: slot s0+3, parity 0, ring Ra
        if (g1w) {
            if (s0 + 3 < 256) {
                gru1(s0 + 3, 0, Ra0, Ra1, Ra2);
                if (s0 + 7 < 256) ld3(s0 + 7, Ra0, Ra1, Ra2);
            }
        } else gru2(s0 + 3, 0);
        wg_barrier();
    }
}

// ---------- K5: FC head  out = relu(o2 @ fc1_w.T + b1) @ fc2_w.T + b2 ----------
__global__ __launch_bounds__(256) void k_fc(const float* __restrict__ o2,
                                            const float* __restrict__ fc1_w,
                                            const float* __restrict__ fc1_b,
                                            const float* __restrict__ fc2_w,
                                            const float* __restrict__ fc2_b,
                                            float* __restrict__ out)
{
    const int lane = threadIdx.x & 63;
    const int wid  = blockIdx.x * 4 + (threadIdx.x >> 6);   // 0..2047

    float w1[64], w2[64];
    {
        const float4* p = (const float4*)(fc1_w + lane * 64);
        #pragma unroll
        for (int i = 0; i < 16; i++) {
            float4 a = p[i]; w1[4*i]=a.x; w1[4*i+1]=a.y; w1[4*i+2]=a.z; w1[4*i+3]=a.w;
        }
    }
    const float b1v = fc1_b[lane];
    float b2v = 0.f;
    if (lane < NOUT) {
        const float4* p = (const float4*)(fc2_w + lane * 64);
        #pragma unroll
        for (int i = 0; i < 16; i++) {
            float4 a = p[i]; w2[4*i]=a.x; w2[4*i+1]=a.y; w2[4*i+2]=a.z; w2[4*i+3]=a.w;
        }
        b2v = fc2_b[lane];
    } else {
        #pragma unroll
        for (int i = 0; i < 64; i++) w2[i] = 0.f;
    }

    for (int r = wid; r < NB * NC; r += 2048) {
        float v = o2[(size_t)r * 64 + lane];
        float y = b1v;
        #pragma unroll
        for (int m = 0; m < 64; m++) y = fmaf(lane_bcast(v, m), w1[m], y);
        y = fmaxf(y, 0.f);
        float o = b2v;
        #pragma unroll
        for (int m = 0; m < 64; m++) o = fmaf(lane_bcast(y, m), w2[m], o);
        if (lane < NOUT) out[(size_t)r * NOUT + lane] = o;
    }
}

// ---------- launch ----------
extern "C" void kernel_launch(void* const* d_in, const int* in_sizes, int n_in,
                              void* d_out, int out_size, void* d_ws, size_t ws_size,
                              hipStream_t stream)
{
    (void)in_sizes; (void)n_in; (void)out_size;
    const float* x       = (const float*)d_in[0];
    const float* conv1_w = (const float*)d_in[1];
    const float* conv1_b = (const float*)d_in[2];
    const float* conv2_w = (const float*)d_in[3];
    const float* conv2_b = (const float*)d_in[4];
    const float* w_ih1   = (const float*)d_in[5];
    const float* w_hh1   = (const float*)d_in[6];
    const float* b_ih1   = (const float*)d_in[7];
    const float* b_hh1   = (const float*)d_in[8];
    const float* w_ih2   = (const float*)d_in[9];
    const float* w_hh2   = (const float*)d_in[10];
    const float* b_ih2   = (const float*)d_in[11];
    const float* b_hh2   = (const float*)d_in[12];
    const float* fc1_w   = (const float*)d_in[13];
    const float* fc1_b   = (const float*)d_in[14];
    const float* fc2_w   = (const float*)d_in[15];
    const float* fc2_b   = (const float*)d_in[16];
    float* out = (float*)d_out;

    // workspace layout (total 219,041,792 B ~ 209 MiB)
    if (ws_size < 219041792ull) return;  // fail "incorrect", not a fault
    char* ws = (char*)d_ws;
    uint16_t* h1      = (uint16_t*)(ws);               // 150,994,944 B  bf16 [bt][y*256+ci]
    uint16_t* featsb  = (uint16_t*)(ws + 150994944);   //  25,165,824 B  bf16 [b*256+co][192]
    uint16_t* g1b     = (uint16_t*)(ws + 176160768);   //  25,165,824 B  bf16 [b*256+j][192]
    float*    o2      = (float*)   (ws + 201326592);   //  16,777,216 B  f32  [b*256+j][64]
    uint16_t* w2b     = (uint16_t*)(ws + 218103808);   //     786,432 B  bf16 [co][y*256+ci]
    uint16_t* w_ih1b  = (uint16_t*)(ws + 218890240);   //      98,304 B  bf16 [g][256]
    uint16_t* w1b     = (uint16_t*)(ws + 218988544);   //      53,248 B  bf16 [co][104] k-pad

    k_cvtw1<<<dim3(52),  256, 0, stream>>>(conv1_w, w1b);
    k_cvtw2<<<dim3(768), 256, 0, stream>>>(conv2_w, w2b);
    k_cvt  <<<dim3(96),  256, 0, stream>>>(w_ih1, w_ih1b, 49152);
    k_conv1_mfma<<<dim3(12, 256), 256, 0, stream>>>(x, w1b, conv1_b, h1);
    // conv2: M=49152 bt, N=256 co (one B-tile), K=1536 (24 steps)
    k_gemm<0><<<dim3(768, 1), 256, 0, stream>>>(h1, w2b, conv2_b, featsb, 24, K2, K2);
    // g1pre: M=192 g, N=65536 btj, K=192 (3 steps)
    k_gemm<1><<<dim3(3, 256), 256, 0, stream>>>(w_ih1b, featsb, b_ih1, g1b, 3, 256, NT);
    k_scan_pipe<<<dim3(16), 512, 0, stream>>>(g1b, w_ih1, w_hh1, b_hh1,
                                              w_ih2, w_hh2, b_ih2, b_hh2, o2);
    k_fc<<<dim3(512), 256, 0, stream>>>(o2, fc1_w, fc1_b, fc2_w, fc2_b, out);
}

// Round 7
// 516.747 us; speedup vs baseline: 1.4702x; 1.1898x over previous
//
#include <hip/hip_runtime.h>
#include <stdint.h>

// Problem constants
#define NB   256     // batch
#define NT   192     // frames
#define NH   64      // hidden
#define NC   256     // conv channels / scan steps
#define NOUT 28
#define K2   1536    // conv2 reduction = 256ci * 6y (re-keyed as y*256+ci)

typedef __attribute__((ext_vector_type(8))) short short8v;  // 8 bf16 (4 VGPR)
typedef __attribute__((ext_vector_type(4))) float f32x4;    // MFMA acc

// ---------- helpers ----------
__device__ __forceinline__ float lane_bcast(float v, int m) {
    return __int_as_float(__builtin_amdgcn_readlane(__float_as_int(v), m));
}
__device__ __forceinline__ uint16_t f2bf(float f) {          // RNE f32->bf16
    uint32_t u = __float_as_uint(f);
    return (uint16_t)((u + 0x7fffu + ((u >> 16) & 1u)) >> 16);
}
__device__ __forceinline__ uint32_t pk2(float a, float b) {
    return (uint32_t)f2bf(a) | ((uint32_t)f2bf(b) << 16);
}
__device__ __forceinline__ float bf2f(uint16_t u) {
    return __uint_as_float((uint32_t)u << 16);
}
// fast gate nonlinearities: v_exp + v_rcp, no IEEE division, branch-free.
// fsig: 4 instrs; ftanh2: 5 instrs. Saturation at +-inf is exact.
__device__ __forceinline__ float fsig(float x) {
    return __builtin_amdgcn_rcpf(1.f + __expf(-x));
}
__device__ __forceinline__ float ftanh2(float x) {
    return fmaf(2.f, __builtin_amdgcn_rcpf(1.f + __expf(-2.f * x)), -1.f);
}
// raw barrier: LDS-ordering only, does NOT drain vmcnt (keeps global prefetch alive)
__device__ __forceinline__ void wg_barrier() {
    asm volatile("s_waitcnt lgkmcnt(0)\n\ts_barrier" ::: "memory");
}
// async global->LDS, 16 B per lane; LDS dest is wave-uniform base + lane*16
__device__ __forceinline__ void gload_lds16(const uint16_t* g, uint16_t* l) {
    __builtin_amdgcn_global_load_lds(
        (const __attribute__((address_space(1))) uint32_t*)(const void*)g,
        (__attribute__((address_space(3))) uint32_t*)(void*)l, 16, 0, 0);
}
// read one MFMA operand fragment from a [rows][64] bf16 LDS tile, XOR-swizzled
__device__ __forceinline__ short8v frag_ld(const uint16_t* tile, int row, int kchunk) {
    const int kc = kchunk ^ (row & 7);
    return *(const short8v*)(tile + row * 64 + kc * 8);
}
// pack 8 consecutive f32 -> short8v (bf16)
__device__ __forceinline__ short8v pack8(const float* p) {
    float4 q0 = *(const float4*)p;
    float4 q1 = *(const float4*)(p + 4);
    union { short8v v; uint32_t u[4]; } r;
    r.u[0] = pk2(q0.x, q0.y); r.u[1] = pk2(q0.z, q0.w);
    r.u[2] = pk2(q1.x, q1.y); r.u[3] = pk2(q1.z, q1.w);
    return r.v;
}

// ---------- K0a: fp32 -> bf16 conversion (n even) ----------
__global__ __launch_bounds__(256) void k_cvt(const float* __restrict__ src,
                                             uint16_t* __restrict__ dst, int n)
{
    int i = blockIdx.x * 256 + threadIdx.x;      // converts 2 elems
    if (2 * i < n) {
        float2 v = *(const float2*)(src + 2 * i);
        ((uint32_t*)dst)[i] = pk2(v.x, v.y);
    }
}

// ---------- K0b: w1 (256,72) fp32 -> w1b_pad (256,104) bf16, k>=72 zero ----------
__global__ __launch_bounds__(256) void k_cvtw1(const float* __restrict__ w1,
                                               uint16_t* __restrict__ dst)
{
    int id = blockIdx.x * 256 + threadIdx.x;     // one u32 pair
    if (id < 256 * 52) {
        int co = id / 52, p = id - co * 52;
        uint32_t v = 0u;
        if (p < 36) {
            float2 q = *(const float2*)(w1 + co * 72 + 2 * p);
            v = pk2(q.x, q.y);
        }
        ((uint32_t*)dst)[id] = v;
    }
}

// ---------- K0c: w2 [co][ci*6+y] fp32 -> w2b [co][y*256+ci] bf16 ----------
__global__ __launch_bounds__(256) void k_cvtw2(const float* __restrict__ w2,
                                               uint16_t* __restrict__ dst)
{
    int id = blockIdx.x * 256 + threadIdx.x;     // one u32 pair
    if (id < 196608) {
        int co  = id / 768;
        int rem = id - co * 768;
        int y   = rem / 128;
        int cp  = rem - y * 128;
        int ci0 = cp * 2;
        float a = w2[(size_t)co * 1536 + ci0 * 6 + y];
        float b = w2[(size_t)co * 1536 + (ci0 + 1) * 6 + y];
        ((uint32_t*)dst)[id] = pk2(a, b);
    }
}

// ---------- K0d: bsum1[192] = b_ih1 + [b_hh1_r, b_hh1_z, 0_n] ----------
// (b_hh1 r/z parts fold linearly into the gate pre-sum; n-part must stay inside
//  the r*(...) term and is applied in-scan.)
__global__ __launch_bounds__(256) void k_bias1(const float* __restrict__ b_ih1,
                                               const float* __restrict__ b_hh1,
                                               float* __restrict__ bsum)
{
    int t = threadIdx.x;
    if (t < 192) bsum[t] = b_ih1[t] + (t < 128 ? b_hh1[t] : 0.f);
}

// ---------- K1: conv1 via implicit-GEMM MFMA ----------
// D[co][m=(lt,y)] = sum_{k=(ci,dt,dr,dw)} W[co][k] * P[m][k];  h1 relu'd, k-order y*256+ci
__global__ __launch_bounds__(256) void k_conv1_mfma(const float* __restrict__ x,
                                                    const uint16_t* __restrict__ w1b,
                                                    const float* __restrict__ b1,
                                                    uint16_t* __restrict__ h1)
{
    __shared__ alignas(16) uint16_t Wt[256 * 104];     // 53248 B (DMA, linear)
    __shared__ alignas(16) uint16_t Pt[96 * 100];      // 19200 B (constructed)
    __shared__ alignas(16) float patch[2 * 18 * 64];   //  9216 B [ci][tt][1+f]
    const int tid  = threadIdx.x;
    const int w    = tid >> 6;
    const int lane = tid & 63;
    const int tblk = blockIdx.x;                       // 0..11
    const int b    = blockIdx.y;                       // 0..255
    const int t0   = tblk * 16;

    // 1) issue W DMA: 3328 16B-chunks, 13 per lane
    #pragma unroll
    for (int i = 0; i < 13; i++) {
        const int cbase = i * 256 + w * 64;
        gload_lds16(w1b + (size_t)(cbase + lane) * 8, &Wt[cbase * 8]);
    }

    // 2) stage fp32 patch (frames t0-1 .. t0+16), zero-pad t boundary
    for (int idx = tid; idx < 2 * 18 * 63; idx += 256) {
        int ci  = idx / 1134;
        int rem = idx - ci * 1134;
        int tt  = rem / 63;
        int f   = rem - tt * 63;
        int gf  = t0 - 1 + tt;
        float v = 0.f;
        if (gf >= 0 && gf < NT) v = x[(size_t)b * 24192 + ci * 12096 + gf * 63 + f];
        patch[ci * 1152 + tt * 64 + 1 + f] = v;
    }
    __syncthreads();   // patch ready (also drains W DMA; fine, one-shot kernel)

    // 3) construct P[m][k]: m=lt*6+y, k=cd*12 + (dr*3+dw), cd=(ci,dt); rows stride 100
    for (int l = 0; l < 3; l++) {
        int idx = tid + l * 256;
        if (idx < 576) {
            int m  = idx / 6;
            int cd = idx - m * 6;
            int ci = cd / 3, dt = cd - ci * 3;
            int lt = m / 6,  y  = m - lt * 6;
            const float* pb = &patch[ci * 1152 + (lt + dt) * 64];
            uint2* dst = (uint2*)(Pt + m * 100 + cd * 12);   // 24B, 8B-aligned
            if (y == 0) {   // rows -3..0: dr<3 zero, dr=3 -> pb[1..3]
                dst[0] = (uint2){0u, 0u};
                dst[1] = (uint2){0u, 0u};
                dst[2] = (uint2){(uint32_t)f2bf(pb[1]) << 16, pk2(pb[2], pb[3])};
            } else {
                const float4* q = (const float4*)(pb + 12 * y - 8);
                float4 q0 = q[0], q1 = q[1], q2 = q[2];
                dst[0] = (uint2){pk2(q0.x, q0.y), pk2(q0.z, q0.w)};
                dst[1] = (uint2){pk2(q1.x, q1.y), pk2(q1.z, q1.w)};
                dst[2] = (uint2){pk2(q2.x, q2.y), pk2(q2.z, q2.w)};
            }
        }
    }
    // zero P k-pad 72..95 (both operands' pad zero => safe vs stale LDS)
    {
        int idx = tid;
        if (idx < 192) {
            int m = idx >> 1, half = idx & 1;
            uint2* dst = (uint2*)(Pt + m * 100 + 72 + half * 12);
            dst[0] = (uint2){0u, 0u};
            dst[1] = (uint2){0u, 0u};
            dst[2] = (uint2){0u, 0u};
        }
    }
    wg_barrier();      // P writes visible (W already drained)

    // 4) GEMM: wave w -> co tiles w*4..w*4+3 (64 co) x all 6 m-tiles, 3 K-steps
    f32x4 acc[4][6];
    #pragma unroll
    for (int i = 0; i < 4; i++)
        #pragma unroll
        for (int j = 0; j < 6; j++) acc[i][j] = (f32x4){0.f, 0.f, 0.f, 0.f};

    #pragma unroll
    for (int kstep = 0; kstep < 3; kstep++) {
        const int kch = kstep * 4 + (lane >> 4);       // chunk 0..11
        short8v wf[4], pf[6];
        #pragma unroll
        for (int at = 0; at < 4; at++)
            wf[at] = *(const short8v*)(Wt + ((w * 4 + at) * 16 + (lane & 15)) * 104 + kch * 8);
        #pragma unroll
        for (int mt = 0; mt < 6; mt++)
            pf[mt] = *(const short8v*)(Pt + (mt * 16 + (lane & 15)) * 100 + kch * 8);
        #pragma unroll
        for (int at = 0; at < 4; at++)
            #pragma unroll
            for (int mt = 0; mt < 6; mt++)
                acc[at][mt] = __builtin_amdgcn_mfma_f32_16x16x32_bf16(
                    wf[at], pf[mt], acc[at][mt], 0, 0, 0);
    }

    // 5) epilogue: D layout col(lane&15)=m, row((lane>>4)*4+reg)=co; relu; h1 k=y*256+ci
    #pragma unroll
    for (int mt = 0; mt < 6; mt++) {
        const int m  = mt * 16 + (lane & 15);
        const int lt = m / 6, y = m - lt * 6;
        uint16_t* rowp = h1 + (size_t)(b * NT + t0 + lt) * K2 + y * 256;
        #pragma unroll
        for (int at = 0; at < 4; at++) {
            const int co0 = (w * 4 + at) * 16 + (lane >> 4) * 4;
            float4 b4 = *(const float4*)&b1[co0];
            f32x4 v = acc[at][mt];
            float r0 = fmaxf(v[0] + b4.x, 0.f), r1 = fmaxf(v[1] + b4.y, 0.f);
            float r2 = fmaxf(v[2] + b4.z, 0.f), r3 = fmaxf(v[3] + b4.w, 0.f);
            *(uint2*)(rowp + co0) = (uint2){pk2(r0, r1), pk2(r2, r3)};
        }
    }
}

// ---------- K2: unified bf16 MFMA GEMM ----------
// C[arow][bcol] = sum_k A[arow][k] * B[bcol][k]  (both operands [entity][k] bf16)
// MODE 0 (conv2): A=h1[bt][1536], B=w2b[co][1536]; out=featsb[(b*256+co)][t] bf16 +b2[co]
// MODE 1 (g1pre): A=w_ih1b[g][256], B=featsb[btj][192]; out=g1b[btj][g] bf16 +bias[g]
template<int MODE>
__global__ __launch_bounds__(256) void k_gemm(const uint16_t* __restrict__ A,
                                              const uint16_t* __restrict__ B,
                                              const float* __restrict__ bias,
                                              uint16_t* __restrict__ out,
                                              int kSteps, int lda, int ldb)
{
    __shared__ alignas(16) uint16_t As[2][64 * 64];     // 16 KB
    __shared__ alignas(16) uint16_t Bs[2][256 * 64];    // 64 KB
    const int tid  = threadIdx.x;
    const int w    = tid >> 6;
    const int lane = tid & 63;
    const int a0   = blockIdx.x * 64;
    const int b0   = blockIdx.y * 256;

    f32x4 acc[4][4];
    #pragma unroll
    for (int i = 0; i < 4; i++)
        #pragma unroll
        for (int j = 0; j < 4; j++) acc[i][j] = (f32x4){0.f, 0.f, 0.f, 0.f};

    auto stage = [&](int buf, int k0) {
        #pragma unroll
        for (int i = 0; i < 2; i++) {                    // A: 512 chunks, 2 instr/wave
            int c   = w * 128 + i * 64 + lane;
            int row = c >> 3;
            int kc  = (c & 7) ^ (row & 7);               // inverse swizzle on SOURCE
            gload_lds16(A + (size_t)(a0 + row) * lda + k0 + kc * 8,
                        &As[buf][(w * 128 + i * 64) * 8]);
        }
        #pragma unroll
        for (int i = 0; i < 8; i++) {                    // B: 2048 chunks, 8 instr/wave
            int c   = w * 512 + i * 64 + lane;
            int row = c >> 3;
            int kc  = (c & 7) ^ (row & 7);
            gload_lds16(B + (size_t)(b0 + row) * ldb + k0 + kc * 8,
                        &Bs[buf][(w * 512 + i * 64) * 8]);
        }
    };

    stage(0, 0);
    for (int t = 0; t < kSteps; ++t) {
        const int cur = t & 1;
        if (t + 1 < kSteps) {
            stage(cur ^ 1, (t + 1) * 64);
            asm volatile("s_waitcnt vmcnt(10)" ::: "memory");  // cur's 10 done, next 10 in flight
        } else {
            asm volatile("s_waitcnt vmcnt(0)" ::: "memory");
        }
        __builtin_amdgcn_sched_barrier(0);
        __builtin_amdgcn_s_barrier();
        __builtin_amdgcn_sched_barrier(0);
        #pragma unroll
        for (int ks = 0; ks < 2; ++ks) {
            short8v af[4], bf[4];
            const int kch = ks * 4 + (lane >> 4);
            #pragma unroll
            for (int rt = 0; rt < 4; rt++)
                af[rt] = frag_ld(As[cur], rt * 16 + (lane & 15), kch);
            #pragma unroll
            for (int ct = 0; ct < 4; ct++)
                bf[ct] = frag_ld(Bs[cur], w * 64 + ct * 16 + (lane & 15), kch);
            #pragma unroll
            for (int rt = 0; rt < 4; rt++)
                #pragma unroll
                for (int ct = 0; ct < 4; ct++)
                    acc[rt][ct] = __builtin_amdgcn_mfma_f32_16x16x32_bf16(
                        af[rt], bf[ct], acc[rt][ct], 0, 0, 0);
        }
        asm volatile("s_waitcnt lgkmcnt(0)" ::: "memory");     // ds_reads done before reuse
        __builtin_amdgcn_sched_barrier(0);
        __builtin_amdgcn_s_barrier();
        __builtin_amdgcn_sched_barrier(0);
    }

    // epilogue: C/D layout col=lane&15, row=(lane>>4)*4+reg  [m89-verified]
    const int rsub = (lane >> 4) * 4;
    #pragma unroll
    for (int rt = 0; rt < 4; rt++) {
        if constexpr (MODE == 0) {
            const int bt = a0 + rt * 16 + rsub;          // 4 consecutive bt (regs 0..3)
            const int bb = bt / NT, tt = bt - bb * NT;   // bt%4==0 -> never straddles b
            #pragma unroll
            for (int ct = 0; ct < 4; ct++) {
                const int co = w * 64 + ct * 16 + (lane & 15);
                const float bv = bias[co];
                f32x4 v = acc[rt][ct];
                uint2 st = { pk2(v[0] + bv, v[1] + bv), pk2(v[2] + bv, v[3] + bv) };
                *(uint2*)&out[(size_t)(bb * 256 + co) * NT + tt] = st;
            }
        } else {
            const int g = a0 + rt * 16 + rsub;           // 4 consecutive gates
            const float4 b4 = *(const float4*)&bias[g];
            #pragma unroll
            for (int ct = 0; ct < 4; ct++) {
                const int btj = b0 + w * 64 + ct * 16 + (lane & 15);
                f32x4 v = acc[rt][ct];
                uint2 st = { pk2(v[0] + b4.x, v[1] + b4.y), pk2(v[2] + b4.z, v[3] + b4.w) };
                *(uint2*)&out[(size_t)btj * NT + g] = st;
            }
        }
    }
}

// ---------- K4: wave-specialized pipelined GRU1+GRU2 scan, 4-deep prefetch ring ----
// 16 blocks x 8 waves; block owns batches b0..b0+15.
// Waves 0-3: GRU1 step j=slot.  Waves 4-7: GRU2 step j2=slot-1 (1-step pipeline).
// Wave q (=w&3) owns h-dims [q*16, q*16+16) with ALL 6 gate components as MFMA
// tiles -> gates fully in-register. h tiles double-buffered by slot parity;
// ONE barrier per slot. g1b pre-values prefetched 4 slots ahead in a named
// register ring. Gate nonlinearities use v_exp+v_rcp (no IEEE division) --
// scan is VALU-issue-bound on its 16 active CUs (round-6 profile).
__global__ __launch_bounds__(512) void k_scan_pipe(const uint16_t* __restrict__ g1b,
                                                   const float* __restrict__ w_ih1,
                                                   const float* __restrict__ w_hh1,
                                                   const float* __restrict__ b_hh1,
                                                   const float* __restrict__ w_ih2,
                                                   const float* __restrict__ w_hh2,
                                                   const float* __restrict__ b_ih2,
                                                   const float* __restrict__ b_hh2,
                                                   float* __restrict__ o2)
{
    __shared__ alignas(16) uint16_t H1[2][16 * 64];   // h1 by slot parity, XOR-swizzled
    __shared__ alignas(16) uint16_t H2[2][16 * 64];   // h2 by slot parity

    const int tid  = threadIdx.x;
    const int w    = tid >> 6;
    const int lane = tid & 63;
    const int g    = lane >> 4;          // 0..3 (k-chunk group / reg-row group)
    const int b    = lane & 15;          // local batch
    const int q    = w & 3;              // h-dim segment
    const bool g1w = (w < 4);
    const int bg   = blockIdx.x * 16 + b;
    const int i0   = q * 16 + g * 4;     // first of 4 h-dims owned by this lane

    // --- A-fragments (weights) in registers, static across all 256 steps ---
    short8v wf[6][2];
    #pragma unroll
    for (int c = 0; c < 6; c++) {
        const int rowc = (c % 3) * 64 + q * 16 + (lane & 15);
        #pragma unroll
        for (int ks = 0; ks < 2; ks++) {
            const int koff = ks * 32 + g * 8;
            const float* src;
            if (g1w) src = (c < 3) ? (w_ih1 + rowc * 256 + 192 + koff)
                                   : (w_hh1 + rowc * 64 + koff);
            else     src = (c < 3) ? (w_ih2 + rowc * 64 + koff)
                                   : (w_hh2 + rowc * 64 + koff);
            wf[c][ks] = pack8(src);
        }
    }
    // --- per-lane gate biases (rz of GRU1 are folded into g1b via k_bias1) ---
    // GRU1: bn1v = b_hh1 n-part (inside r*(.)).
    // GRU2: brsv/bzsv = b_ih2+b_hh2 (rz sums); bn1v = b_ih2 n; bn2v = b_hh2 n.
    float bn1v[4], bn2v[4], brsv[4], bzsv[4];
    #pragma unroll
    for (int r = 0; r < 4; r++) {
        if (g1w) {
            bn1v[r] = b_hh1[128 + i0 + r];
            bn2v[r] = 0.f; brsv[r] = 0.f; bzsv[r] = 0.f;
        } else {
            brsv[r] = b_ih2[i0 + r] + b_hh2[i0 + r];
            bzsv[r] = b_ih2[64 + i0 + r] + b_hh2[64 + i0 + r];
            bn1v[r] = b_ih2[128 + i0 + r];
            bn2v[r] = b_hh2[128 + i0 + r];
        }
    }

    // --- zero both parities of both h tiles ---
    {
        uint32_t* z1 = (uint32_t*)H1;
        uint32_t* z2 = (uint32_t*)H2;
        for (int idx = tid; idx < 1024; idx += 512) { z1[idx] = 0u; z2[idx] = 0u; }
    }
    __syncthreads();

    float hs0 = 0.f, hs1 = 0.f, hs2 = 0.f, hs3 = 0.f;   // own h-state (h1 or h2 dims)

    const uint16_t* gbase = g1b + (size_t)bg * 256 * 192 + i0;

    // GRU1 cell for slot j (parity par), pre-values P0/P1/P2 (r/z/n gate quads)
    auto gru1 = [&](int slot, int par, uint2 P0, uint2 P1, uint2 P2) {
        const uint16_t* hrd = H1[par ^ 1] + b * 64;
        short8v f0 = *(const short8v*)(hrd + ((0 + g) ^ (b & 7)) * 8);
        short8v f1 = *(const short8v*)(hrd + ((4 + g) ^ (b & 7)) * 8);
        f32x4 a[6];
        #pragma unroll
        for (int c = 0; c < 6; c++) {
            a[c] = __builtin_amdgcn_mfma_f32_16x16x32_bf16(
                wf[c][0], f0, (f32x4){0.f, 0.f, 0.f, 0.f}, 0, 0, 0);
            a[c] = __builtin_amdgcn_mfma_f32_16x16x32_bf16(
                wf[c][1], f1, a[c], 0, 0, 0);
        }
        float pr[4], pz[4], pnn[4];
        pr[0]=bf2f((uint16_t)P0.x);  pr[1]=bf2f((uint16_t)(P0.x>>16));
        pr[2]=bf2f((uint16_t)P0.y);  pr[3]=bf2f((uint16_t)(P0.y>>16));
        pz[0]=bf2f((uint16_t)P1.x);  pz[1]=bf2f((uint16_t)(P1.x>>16));
        pz[2]=bf2f((uint16_t)P1.y);  pz[3]=bf2f((uint16_t)(P1.y>>16));
        pnn[0]=bf2f((uint16_t)P2.x); pnn[1]=bf2f((uint16_t)(P2.x>>16));
        pnn[2]=bf2f((uint16_t)P2.y); pnn[3]=bf2f((uint16_t)(P2.y>>16));

        float nh[4];
        float hsv[4] = {hs0, hs1, hs2, hs3};
        #pragma unroll
        for (int r = 0; r < 4; r++) {
            float rr = fsig((pr[r] + a[0][r]) + a[3][r]);          // b_ih1+b_hh1 folded
            float zz = fsig((pz[r] + a[1][r]) + a[4][r]);
            float nn = ftanh2(fmaf(rr, a[5][r] + bn1v[r], pnn[r] + a[2][r]));
            nh[r] = nn + zz * (hsv[r] - nn);
        }
        hs0 = nh[0]; hs1 = nh[1]; hs2 = nh[2]; hs3 = nh[3];
        const int cd = q * 2 + (g >> 1);
        *(uint2*)(H1[par] + b * 64 + ((cd) ^ (b & 7)) * 8 + (g & 1) * 4) =
            (uint2){pk2(nh[0], nh[1]), pk2(nh[2], nh[3])};
    };

    // GRU2 cell for slot (j2 = slot-1, parity par)
    auto gru2 = [&](int slot, int par) {
        const int j2 = slot - 1;
        const uint16_t* xr = H1[par ^ 1] + b * 64;
        const uint16_t* hr = H2[par ^ 1] + b * 64;
        short8v x0 = *(const short8v*)(xr + ((0 + g) ^ (b & 7)) * 8);
        short8v x1 = *(const short8v*)(xr + ((4 + g) ^ (b & 7)) * 8);
        short8v y0 = *(const short8v*)(hr + ((0 + g) ^ (b & 7)) * 8);
        short8v y1 = *(const short8v*)(hr + ((4 + g) ^ (b & 7)) * 8);
        f32x4 a[6];
        #pragma unroll
        for (int c = 0; c < 3; c++) {
            a[c] = __builtin_amdgcn_mfma_f32_16x16x32_bf16(
                wf[c][0], x0, (f32x4){0.f, 0.f, 0.f, 0.f}, 0, 0, 0);
            a[c] = __builtin_amdgcn_mfma_f32_16x16x32_bf16(
                wf[c][1], x1, a[c], 0, 0, 0);
        }
        #pragma unroll
        for (int c = 3; c < 6; c++) {
            a[c] = __builtin_amdgcn_mfma_f32_16x16x32_bf16(
                wf[c][0], y0, (f32x4){0.f, 0.f, 0.f, 0.f}, 0, 0, 0);
            a[c] = __builtin_amdgcn_mfma_f32_16x16x32_bf16(
                wf[c][1], y1, a[c], 0, 0, 0);
        }
        float nh[4];
        float hsv[4] = {hs0, hs1, hs2, hs3};
        #pragma unroll
        for (int r = 0; r < 4; r++) {
            float rr = fsig((a[0][r] + a[3][r]) + brsv[r]);
            float zz = fsig((a[1][r] + a[4][r]) + bzsv[r]);
            float nn = ftanh2(fmaf(rr, a[5][r] + bn2v[r], a[2][r] + bn1v[r]));
            nh[r] = nn + zz * (hsv[r] - nn);
        }
        hs0 = nh[0]; hs1 = nh[1]; hs2 = nh[2]; hs3 = nh[3];
        const int cd = q * 2 + (g >> 1);
        *(uint2*)(H2[par] + b * 64 + ((cd) ^ (b & 7)) * 8 + (g & 1) * 4) =
            (uint2){pk2(nh[0], nh[1]), pk2(nh[2], nh[3])};
        *(float4*)&o2[((size_t)bg * 256 + j2) * 64 + i0] =
            make_float4(nh[0], nh[1], nh[2], nh[3]);
    };

    auto ld3 = [&](int j, uint2& A, uint2& B2, uint2& C) {
        const uint16_t* nb = gbase + (size_t)j * 192;
        A  = *(const uint2*)(nb);
        B2 = *(const uint2*)(nb + 64);
        C  = *(const uint2*)(nb + 128);
    };

    // prefetch ring: 4 named triples (slot s uses ring slot s&3)
    uint2 Ra0, Ra1, Ra2, Rb0, Rb1, Rb2, Rc0, Rc1, Rc2, Rd0, Rd1, Rd2;
    if (g1w) {
        ld3(0, Ra0, Ra1, Ra2); ld3(1, Rb0, Rb1, Rb2);
        ld3(2, Rc0, Rc1, Rc2); ld3(3, Rd0, Rd1, Rd2);
    }

    // slot 0 (GRU1 only, parity 0)
    if (g1w) { gru1(0, 0, Ra0, Ra1, Ra2); ld3(4, Ra0, Ra1, Ra2); }
    wg_barrier();

    for (int m = 0; m < 64; ++m) {
        const int s0 = 4 * m + 1;
        // sub-slot k=0: slot s0, parity 1, ring Rb
        if (g1w) {
            if (s0 < 256) {
                gru1(s0, 1, Rb0, Rb1, Rb2);
                if (s0 + 4 < 256) ld3(s0 + 4, Rb0, Rb1, Rb2);
            }
        } else gru2(s0, 1);
        wg_barrier();
        // sub-slot k=1: slot s0+1, parity 0, ring Rc
        if (g1w) {
            if (s0 + 1 < 256) {
                gru1(s0 + 1, 0, Rc0, Rc1, Rc2);
                if (s0 + 5 < 256) ld3(s0 + 5, Rc0, Rc1, Rc2);
            }
        } else gru2(s0 + 1, 0);
        wg_barrier();
        // sub-slot k=2: slot s0+2, parity 1, ring Rd
        if (g1w) {
            if (s0 + 2 < 256) {
                gru1(s0 + 2, 1, Rd0, Rd1, Rd2);
                if (s0 + 6 < 256) ld3(s0 + 6, Rd0, Rd1, Rd2);
            }
        } else gru2(s0 + 2, 1);
        wg_barrier();
        // sub-slot k=3: slot s0+3, parity 0, ring Ra
        if (g1w) {
            if (s0 + 3 < 256) {
                gru1(s0 + 3, 0, Ra0, Ra1, Ra2);
                if (s0 + 7 < 256) ld3(s0 + 7, Ra0, Ra1, Ra2);
            }
        } else gru2(s0 + 3, 0);
        wg_barrier();
    }
}

// ---------- K5: FC head  out = relu(o2 @ fc1_w.T + b1) @ fc2_w.T + b2 ----------
__global__ __launch_bounds__(256) void k_fc(const float* __restrict__ o2,
                                            const float* __restrict__ fc1_w,
                                            const float* __restrict__ fc1_b,
                                            const float* __restrict__ fc2_w,
                                            const float* __restrict__ fc2_b,
                                            float* __restrict__ out)
{
    const int lane = threadIdx.x & 63;
    const int wid  = blockIdx.x * 4 + (threadIdx.x >> 6);   // 0..2047

    float w1[64], w2[64];
    {
        const float4* p = (const float4*)(fc1_w + lane * 64);
        #pragma unroll
        for (int i = 0; i < 16; i++) {
            float4 a = p[i]; w1[4*i]=a.x; w1[4*i+1]=a.y; w1[4*i+2]=a.z; w1[4*i+3]=a.w;
        }
    }
    const float b1v = fc1_b[lane];
    float b2v = 0.f;
    if (lane < NOUT) {
        const float4* p = (const float4*)(fc2_w + lane * 64);
        #pragma unroll
        for (int i = 0; i < 16; i++) {
            float4 a = p[i]; w2[4*i]=a.x; w2[4*i+1]=a.y; w2[4*i+2]=a.z; w2[4*i+3]=a.w;
        }
        b2v = fc2_b[lane];
    } else {
        #pragma unroll
        for (int i = 0; i < 64; i++) w2[i] = 0.f;
    }

    for (int r = wid; r < NB * NC; r += 2048) {
        float v = o2[(size_t)r * 64 + lane];
        float y = b1v;
        #pragma unroll
        for (int m = 0; m < 64; m++) y = fmaf(lane_bcast(v, m), w1[m], y);
        y = fmaxf(y, 0.f);
        float o = b2v;
        #pragma unroll
        for (int m = 0; m < 64; m++) o = fmaf(lane_bcast(y, m), w2[m], o);
        if (lane < NOUT) out[(size_t)r * NOUT + lane] = o;
    }
}

// ---------- launch ----------
extern "C" void kernel_launch(void* const* d_in, const int* in_sizes, int n_in,
                              void* d_out, int out_size, void* d_ws, size_t ws_size,
                              hipStream_t stream)
{
    (void)in_sizes; (void)n_in; (void)out_size;
    const float* x       = (const float*)d_in[0];
    const float* conv1_w = (const float*)d_in[1];
    const float* conv1_b = (const float*)d_in[2];
    const float* conv2_w = (const float*)d_in[3];
    const float* conv2_b = (const float*)d_in[4];
    const float* w_ih1   = (const float*)d_in[5];
    const float* w_hh1   = (const float*)d_in[6];
    const float* b_ih1   = (const float*)d_in[7];
    const float* b_hh1   = (const float*)d_in[8];
    const float* w_ih2   = (const float*)d_in[9];
    const float* w_hh2   = (const float*)d_in[10];
    const float* b_ih2   = (const float*)d_in[11];
    const float* b_hh2   = (const float*)d_in[12];
    const float* fc1_w   = (const float*)d_in[13];
    const float* fc1_b   = (const float*)d_in[14];
    const float* fc2_w   = (const float*)d_in[15];
    const float* fc2_b   = (const float*)d_in[16];
    float* out = (float*)d_out;

    // workspace layout (total 219,042,560 B ~ 209 MiB)
    if (ws_size < 219042560ull) return;  // fail "incorrect", not a fault
    char* ws = (char*)d_ws;
    uint16_t* h1      = (uint16_t*)(ws);               // 150,994,944 B  bf16 [bt][y*256+ci]
    uint16_t* featsb  = (uint16_t*)(ws + 150994944);   //  25,165,824 B  bf16 [b*256+co][192]
    uint16_t* g1b     = (uint16_t*)(ws + 176160768);   //  25,165,824 B  bf16 [b*256+j][192]
    float*    o2      = (float*)   (ws + 201326592);   //  16,777,216 B  f32  [b*256+j][64]
    uint16_t* w2b     = (uint16_t*)(ws + 218103808);   //     786,432 B  bf16 [co][y*256+ci]
    uint16_t* w_ih1b  = (uint16_t*)(ws + 218890240);   //      98,304 B  bf16 [g][256]
    uint16_t* w1b     = (uint16_t*)(ws + 218988544);   //      53,248 B  bf16 [co][104] k-pad
    float*    bsum1   = (float*)   (ws + 219041792);   //         768 B  f32  bias fold

    k_cvtw1<<<dim3(52),  256, 0, stream>>>(conv1_w, w1b);
    k_cvtw2<<<dim3(768), 256, 0, stream>>>(conv2_w, w2b);
    k_cvt  <<<dim3(96),  256, 0, stream>>>(w_ih1, w_ih1b, 49152);
    k_bias1<<<dim3(1),   256, 0, stream>>>(b_ih1, b_hh1, bsum1);
    k_conv1_mfma<<<dim3(12, 256), 256, 0, stream>>>(x, w1b, conv1_b, h1);
    // conv2: M=49152 bt, N=256 co (one B-tile), K=1536 (24 steps)
    k_gemm<0><<<dim3(768, 1), 256, 0, stream>>>(h1, w2b, conv2_b, featsb, 24, K2, K2);
    // g1pre: M=192 g, N=65536 btj, K=192 (3 steps); bias = b_ih1 + b_hh1(rz) folded
    k_gemm<1><<<dim3(3, 256), 256, 0, stream>>>(w_ih1b, featsb, bsum1, g1b, 3, 256, NT);
    k_scan_pipe<<<dim3(16), 512, 0, stream>>>(g1b, w_ih1, w_hh1, b_hh1,
                                              w_ih2, w_hh2, b_ih2, b_hh2, o2);
    k_fc<<<dim3(512), 256, 0, stream>>>(o2, fc1_w, fc1_b, fc2_w, fc2_b, out);
}